// Round 11
// baseline (611.642 us; speedup 1.0000x reference)
//
#include <hip/hip_runtime.h>
#include <math.h>

#define BB 4
#define LL 2048
#define DD 512
#define CC 64      // chunk length
#define NC 32      // number of chunks
#define VB 4       // v-columns owned per workgroup
#define EPSF 1e-5f

typedef unsigned int u32;
typedef unsigned short u16;
typedef __attribute__((ext_vector_type(4))) u32 u32x4;
typedef __attribute__((ext_vector_type(4))) float f32x4;
typedef __attribute__((ext_vector_type(8))) __bf16 bf16x8;

__device__ __forceinline__ u16 f2bf(float f) {           // native RNE cvt
  return __builtin_bit_cast(u16, (__bf16)f);
}
__device__ __forceinline__ int sx6(int s) { return (s ^ (s >> 3)) & 7; }
__device__ __forceinline__ bf16x8 ldf(const u16* p) {
  return __builtin_bit_cast(bf16x8, *(const u32x4*)p);
}
__device__ __forceinline__ bf16x8 bcv(u32x4 v) { return __builtin_bit_cast(bf16x8, v); }

__device__ __forceinline__ void gld16(u16* lds, const u16* g) {
  __builtin_amdgcn_global_load_lds(
      (const __attribute__((address_space(1))) u32*)g,
      (__attribute__((address_space(3))) u32*)lds, 16, 0, 0);
}
// barrier that drains only LDS (keeps global loads in flight)
__device__ __forceinline__ void barrier_lgkm() {
  asm volatile("s_waitcnt lgkmcnt(0)" ::: "memory");
  __builtin_amdgcn_sched_barrier(0);
  __builtin_amdgcn_s_barrier();
  __builtin_amdgcn_sched_barrier(0);
}
__device__ __forceinline__ void barrier_all() {
  asm volatile("s_waitcnt vmcnt(0) lgkmcnt(0)" ::: "memory");
  __builtin_amdgcn_sched_barrier(0);
  __builtin_amdgcn_s_barrier();
  __builtin_amdgcn_sched_barrier(0);
}

// ---------------------------------------------------------------------------
// K1b: W -> bf16 (row-major)
// ---------------------------------------------------------------------------
__global__ __launch_bounds__(256) void k_cvtW(const float* __restrict__ W,
                                              u16* __restrict__ wbb) {
  int idx = (blockIdx.x * 256 + threadIdx.x) * 8;
  float4 a = *(const float4*)(W + idx);
  float4 b = *(const float4*)(W + idx + 4);
  float v[8] = {a.x, a.y, a.z, a.w, b.x, b.y, b.z, b.w};
  u32x4 pk;
#pragma unroll
  for (int j = 0; j < 4; ++j)
    pk[j] = (u32)f2bf(v[2 * j]) | ((u32)f2bf(v[2 * j + 1]) << 16);
  *(u32x4*)(wbb + idx) = pk;
}

// ---------------------------------------------------------------------------
// K2: fused per-(b,chunk) prep (unchanged from R10):
//   tanh(x-chunk) -> Kl LDS + kbs global (pre-swizzled bf16 rows)
//   G = K K^T (MFMA); T = (I+A)^{-1} (fwd subst, 4 lanes/col)
//   tbs[s][r] = lam^{63-s}*beta*T ; tcs = -lam^{63-s}*beta*T*lam^{r+1}
//   p1g = Mt.(beta*T) ; p2g = Mt.(-beta*T*diag(lam^{r+1})) ; kbt = K^T swz
// ---------------------------------------------------------------------------
__global__ __launch_bounds__(256) void k_prep3(const float* __restrict__ x,
                                               const float* __restrict__ eta_p,
                                               const float* __restrict__ ll_p,
                                               u16* __restrict__ kbs,
                                               u16* __restrict__ tbs,
                                               u16* __restrict__ tcs,
                                               u16* __restrict__ p1g,
                                               u16* __restrict__ p2g,
                                               u16* __restrict__ kbt) {
  __shared__ __align__(16) u16 Kl[CC * DD];   // 64 KB
  __shared__ float Gl[64 * 64];
  __shared__ float Gs[64 * 64];
  __shared__ float Tl[64 * 65];
  __shared__ __align__(16) u16 MtL[64 * 64];
  __shared__ __align__(16) u16 TbT[64 * 64];
  __shared__ __align__(16) u16 TcT[64 * 64];
  __shared__ float pw[72];
  int bc = blockIdx.x;
  int b = bc >> 5, c = bc & 31;
  int tid = threadIdx.x;
  int wid = tid >> 6, lane = tid & 63;
  int lo = lane & 15, hi = lane >> 4;
  float beta = *eta_p;
  float lam = 1.f / (1.f + expf(-*ll_p));
  if (tid <= 64) pw[tid] = powf(lam, (float)tid);
  for (int i = tid; i < 64 * 65; i += 256) Tl[i] = 0.f;
  // ---- tanh + pack ----
  const float* xg = x + (size_t)(b * LL + c * CC) * DD;
  u16* kbs_c = kbs + (size_t)(b * LL + c * CC) * DD;
#pragma unroll
  for (int i = 0; i < 16; ++i) {
    int idx = tid + i * 256;
    int r = idx >> 6, k8 = (idx & 63) * 8;
    const float* xp = xg + (size_t)r * DD + k8;
    float4 a = *(const float4*)xp;
    float4 b4 = *(const float4*)(xp + 4);
    float v[8] = {a.x, a.y, a.z, a.w, b4.x, b4.y, b4.z, b4.w};
    u32x4 pk;
#pragma unroll
    for (int j = 0; j < 4; ++j)
      pk[j] = (u32)f2bf(tanhf(v[2 * j])) | ((u32)f2bf(tanhf(v[2 * j + 1])) << 16);
    int off = r * DD + (k8 ^ (sx6(r) << 3));
    *(u32x4*)(Kl + off) = pk;
    *(u32x4*)(kbs_c + off) = pk;
  }
  __syncthreads();
  // ---- G = K K^T ----
  {
    f32x4 acc[4] = {{0.f,0.f,0.f,0.f},{0.f,0.f,0.f,0.f},{0.f,0.f,0.f,0.f},{0.f,0.f,0.f,0.f}};
    int t = 16 * wid + lo;
    int mT = sx6(t) << 3;
#pragma unroll
    for (int kq = 0; kq < 16; ++kq) {
      int col = hi * 8 + kq * 32;
      bf16x8 aF = ldf(Kl + t * DD + (col ^ mT));
#pragma unroll
      for (int sb = 0; sb < 4; ++sb) {
        int s = 16 * sb + lo;
        bf16x8 bF = ldf(Kl + s * DD + (col ^ (sx6(s) << 3)));
        acc[sb] = __builtin_amdgcn_mfma_f32_16x16x32_bf16(aF, bF, acc[sb], 0, 0, 0);
      }
    }
#pragma unroll
    for (int sb = 0; sb < 4; ++sb)
#pragma unroll
      for (int r = 0; r < 4; ++r)
        Gl[(16 * wid + 4 * hi + r) * 64 + 16 * sb + lo] = acc[sb][r];
  }
  __syncthreads();
#pragma unroll
  for (int i = 0; i < 16; ++i) {
    int idx = tid + i * 256;
    int tq = idx >> 6, sq = idx & 63;
    Gs[idx] = (sq < tq) ? beta * pw[tq - sq] * Gl[idx] : 0.f;
  }
  __syncthreads();
  // ---- forward substitution ----
  {
    int q = hi;
    int j = 16 * wid + lo;
    for (int t = 0; t < 64; ++t) {
      float ps = 0.f;
#pragma unroll
      for (int i = 0; i < 16; ++i) {
        int s = 16 * q + i;
        ps = fmaf(Gs[t * 64 + s], Tl[s * 65 + j], ps);
      }
      ps += __shfl_xor(ps, 16, 64);
      ps += __shfl_xor(ps, 32, 64);
      if (q == 0) Tl[t * 65 + j] = ((t == j) ? 1.f : 0.f) - ps;
    }
  }
  __syncthreads();
  // ---- tbs/tcs + LDS tiles for P GEMMs ----
  u16* tbso = tbs + (size_t)bc * 4096;
  u16* tcso = tcs + (size_t)bc * 4096;
#pragma unroll
  for (int i = 0; i < 16; ++i) {
    int idx = tid + i * 256;
    int s = idx >> 6, r = idx & 63;
    float tv = Tl[s * 65 + r];
    float sc = pw[63 - s] * beta;
    tbso[idx] = f2bf(sc * tv);
    tcso[idx] = f2bf(-sc * pw[r + 1] * tv);
    int swz = r ^ (sx6(s) << 3);
    float mtv = (r < s) ? pw[s - r] * Gl[s * 64 + r]
                        : ((r == s) ? Gl[s * 64 + r] : 0.f);
    MtL[s * 64 + swz] = f2bf(mtv);
    float tvT = Tl[r * 65 + s];
    TbT[s * 64 + swz] = f2bf(beta * tvT);
    TcT[s * 64 + swz] = f2bf(-beta * pw[s + 1] * tvT);
  }
  __syncthreads();
  // ---- P1 = Mt.Tb, P2 = Mt.Tc ----
  {
    f32x4 p1a[4], p2a[4];
#pragma unroll
    for (int rt = 0; rt < 4; ++rt) {
      p1a[rt] = (f32x4){0.f, 0.f, 0.f, 0.f};
      p2a[rt] = (f32x4){0.f, 0.f, 0.f, 0.f};
    }
    int srow = 16 * wid + lo;
    int aswz = sx6(srow) << 3;
#pragma unroll
    for (int km = 0; km < 2; ++km) {
      int mo = hi * 8 + km * 32;
      bf16x8 aF = ldf(MtL + srow * 64 + (mo ^ aswz));
#pragma unroll
      for (int rt = 0; rt < 4; ++rt) {
        int rrow = 16 * rt + lo;
        int bswz = sx6(rrow) << 3;
        p1a[rt] = __builtin_amdgcn_mfma_f32_16x16x32_bf16(
            aF, ldf(TbT + rrow * 64 + (mo ^ bswz)), p1a[rt], 0, 0, 0);
        p2a[rt] = __builtin_amdgcn_mfma_f32_16x16x32_bf16(
            aF, ldf(TcT + rrow * 64 + (mo ^ bswz)), p2a[rt], 0, 0, 0);
      }
    }
    u16* p1o = p1g + (size_t)bc * 4096;
    u16* p2o = p2g + (size_t)bc * 4096;
#pragma unroll
    for (int rt = 0; rt < 4; ++rt)
#pragma unroll
      for (int rg = 0; rg < 4; ++rg) {
        int s = 16 * wid + 4 * hi + rg;
        int r = 16 * rt + lo;
        p1o[s * 64 + r] = f2bf(p1a[rt][rg]);
        p2o[s * 64 + r] = f2bf(p2a[rt][rg]);
      }
  }
  // ---- kbt = K^T, swizzled ----
  u16* ktb = kbt + (size_t)bc * CC * DD;
#pragma unroll
  for (int rr = 0; rr < 2; ++rr) {
    int k = rr * 256 + tid;
    int kbase = k & ~7, klo = k & 7;
    int mk = sx6(k) << 3;
#pragma unroll
    for (int g = 0; g < 8; ++g) {
      u32 w4[4];
#pragma unroll
      for (int p = 0; p < 4; ++p) {
        int s0 = g * 8 + 2 * p;
        u16 e0 = Kl[s0 * DD + (kbase ^ (sx6(s0) << 3)) + klo];
        u16 e1 = Kl[(s0 + 1) * DD + (kbase ^ (sx6(s0 + 1) << 3)) + klo];
        w4[p] = (u32)e0 | ((u32)e1 << 16);
      }
      *(u32x4*)(ktb + (size_t)k * 64 + ((8 * g) ^ mk)) = (u32x4){w4[0], w4[1], w4[2], w4[3]};
    }
  }
}

// ---------------------------------------------------------------------------
// K3: MFMA chunked scan vA. VB=4, 512 WGs (2 per CU -> 4 waves/SIMD).
//   M-dim packing: rows 0-3 = S^T, rows 4-7 = W, rows 8-15 = zero.
//   Schedule: UV(8) -> bar -> reduce (+kB prefetch) -> bar ->
//             B(kh0) || C+y(kh1) -> bar -> D(8) (+prefetch) -> bar
// ---------------------------------------------------------------------------
__global__ __launch_bounds__(512, 4) void k_scanA(const u16* __restrict__ kbs,
                                                  const u16* __restrict__ kbt,
                                                  const u16* __restrict__ wbb,
                                                  const u16* __restrict__ tbs,
                                                  const u16* __restrict__ tcs,
                                                  const u16* __restrict__ p1g,
                                                  const u16* __restrict__ p2g,
                                                  const float* __restrict__ ll_p,
                                                  float* __restrict__ y) {
  __shared__ __align__(16) u16 Sb[16 * DD];       // rows0-3 S, 4-7 W, 8-15 zero
  __shared__ __align__(16) float Up[2][64][12];   // fp32 partials [kh][s][m0-7]
  __shared__ __align__(16) u16 Vt[16 * 64];
  __shared__ __align__(16) u16 Ut[16 * 64];
  __shared__ __align__(16) u16 Ws[16 * 64];

  int b = blockIdx.x >> 7;
  int vb = blockIdx.x & 127;
  int v0 = vb * VB;
  int tid = threadIdx.x;
  int wid = tid >> 6, lane = tid & 63;
  int wq = wid & 3, kh = wid >> 2;
  int lo = lane & 15, hi = lane >> 4;
  int sidx = 16 * wq + lo;
  int mS = sx6(sidx) << 3;     // swizzle for kbs row sidx
  int mLo = sx6(lo) << 3;      // swizzle for LDS row lo
  int kOff = kh * 256;

  float lam = 1.f / (1.f + expf(-*ll_p));
  float lam64 = powf(lam, 64.f);
  float csc = powf(lam, (float)(sidx + 1));

  // ---- init LDS ----
  {
    u32x4 z = {0u, 0u, 0u, 0u};
    if (tid < 256) *((u32x4*)Sb + tid) = z;        // rows 0-3
    *((u32x4*)Sb + 512 + tid) = z;                 // rows 8-15
    if (tid < 384) {
      u16* base = (tid >> 7) == 0 ? Vt : (tid >> 7) == 1 ? Ut : Ws;
      *((u32x4*)base + (tid & 127)) = z;
    }
    if (wid < 4) {  // W rows v0..v0+3 into Sb rows 4..7
      u32x4 wrow = *(const u32x4*)(wbb + (size_t)(v0 + wid) * DD + lane * 8);
      *(u32x4*)(Sb + (size_t)(4 + wid) * DD + ((lane * 8) ^ (sx6(4 + wid) << 3))) = wrow;
    }
  }
  const u16* kb_b = kbs + (size_t)b * LL * DD;
  float* yb = y + (size_t)b * LL * DD;

  // ---- prologue global loads: kB chunk0, kt chunk0, frames chunk0 ----
  u32x4 kB[8];
#pragma unroll
  for (int kq = 0; kq < 8; ++kq)
    kB[kq] = *(const u32x4*)(kb_b + (size_t)sidx * DD +
                             ((kOff + hi * 8 + kq * 32) ^ mS));
  u32x4 kt0[4], kt1[4], fA0, fA1, fB0, fB1;
  {
    const u16* ktc = kbt + (size_t)(b * NC + 0) * CC * DD;
#pragma unroll
    for (int t = 0; t < 4; ++t) {
      int k = 16 * (4 * wid + t) + lo;
      const u16* rowp = ktc + (size_t)k * 64;
      int m = sx6(k) << 3;
      kt0[t] = *(const u32x4*)(rowp + ((8 * hi) ^ m));
      kt1[t] = *(const u32x4*)(rowp + ((8 * hi + 32) ^ m));
    }
    size_t tbase = ((size_t)(b * NC + 0) * 64 + sidx) * 64 + hi * 8;
    const u16* mA = (kh == 0) ? tbs : p1g;
    const u16* mB = (kh == 0) ? tcs : p2g;
    fA0 = *(const u32x4*)(mA + tbase);
    fA1 = *(const u32x4*)(mA + tbase + 32);
    fB0 = *(const u32x4*)(mB + tbase);
    fB1 = *(const u32x4*)(mB + tbase + 32);
  }
  f32x4 Sa[4];
#pragma unroll
  for (int t = 0; t < 4; ++t) Sa[t] = (f32x4){0.f, 0.f, 0.f, 0.f};
  barrier_all();

  for (int c = 0; c < NC; ++c) {
    // ---- phase UV: [U;V] partials, K from regs ----
    {
      f32x4 A0 = {0.f,0.f,0.f,0.f}, A1 = {0.f,0.f,0.f,0.f};
#pragma unroll
      for (int kq = 0; kq < 8; ++kq) {
        int col = kOff + hi * 8 + kq * 32;
        bf16x8 sA = ldf(Sb + lo * DD + (col ^ mLo));
        if (kq & 1) A1 = __builtin_amdgcn_mfma_f32_16x16x32_bf16(sA, bcv(kB[kq]), A1, 0, 0, 0);
        else        A0 = __builtin_amdgcn_mfma_f32_16x16x32_bf16(sA, bcv(kB[kq]), A0, 0, 0, 0);
      }
      f32x4 F = A0 + A1;
      if (hi < 2) *(f32x4*)&Up[kh][sidx][4 * hi] = F;
    }
    barrier_lgkm();
    // ---- prefetch kB for c+1 (regs free after UV) ----
    if (c + 1 < NC) {
      const u16* src = kb_b + ((size_t)(c + 1) * CC + sidx) * DD;
#pragma unroll
      for (int kq = 0; kq < 8; ++kq)
        kB[kq] = *(const u32x4*)(src + ((kOff + hi * 8 + kq * 32) ^ mS));
    }
    // ---- reduce k-halves: hi=0 -> U rows 0-3, hi=1 -> V rows 0-3 ----
    f32x4 Fr = {0.f, 0.f, 0.f, 0.f};
    if (hi < 2) {
      f32x4 a = *(const f32x4*)&Up[0][sidx][4 * hi];
      f32x4 bq = *(const f32x4*)&Up[1][sidx][4 * hi];
      Fr = a + bq;
      if (kh == 0) {
        if (hi == 0) {
#pragma unroll
          for (int r = 0; r < 4; ++r)
            Ut[r * 64 + (sidx ^ (sx6(r) << 3))] = f2bf(Fr[r]);
        } else {
#pragma unroll
          for (int r = 0; r < 4; ++r)
            Vt[r * 64 + (sidx ^ (sx6(r) << 3))] = f2bf(Fr[r]);
        }
      }
    }
    barrier_lgkm();
    // ---- B (kh0) || C+y (kh1) ----
    {
      bf16x8 vf0 = ldf(Vt + lo * 64 + ((hi * 8) ^ mLo));
      bf16x8 vf1 = ldf(Vt + lo * 64 + ((hi * 8 + 32) ^ mLo));
      bf16x8 uf0 = ldf(Ut + lo * 64 + ((hi * 8) ^ mLo));
      bf16x8 uf1 = ldf(Ut + lo * 64 + ((hi * 8 + 32) ^ mLo));
      if (kh == 0) {
        f32x4 Wa0 = {0.f,0.f,0.f,0.f}, Wa1 = {0.f,0.f,0.f,0.f};
        Wa0 = __builtin_amdgcn_mfma_f32_16x16x32_bf16(vf0, bcv(fA0), Wa0, 0, 0, 0);
        Wa1 = __builtin_amdgcn_mfma_f32_16x16x32_bf16(vf1, bcv(fA1), Wa1, 0, 0, 0);
        Wa0 = __builtin_amdgcn_mfma_f32_16x16x32_bf16(uf0, bcv(fB0), Wa0, 0, 0, 0);
        Wa1 = __builtin_amdgcn_mfma_f32_16x16x32_bf16(uf1, bcv(fB1), Wa1, 0, 0, 0);
        f32x4 Wa = Wa0 + Wa1;
        if (hi == 0) {
#pragma unroll
          for (int r = 0; r < 4; ++r)
            Ws[r * 64 + (sidx ^ (sx6(r) << 3))] = f2bf(Wa[r]);
        }
      } else {
        // V lives in hi=1 lanes' Fr; bring to hi=0 via lane^16
        f32x4 Vsw;
#pragma unroll
        for (int r = 0; r < 4; ++r) Vsw[r] = __shfl_xor(Fr[r], 16, 64);
        f32x4 Oa, Ob = {0.f,0.f,0.f,0.f};
#pragma unroll
        for (int r = 0; r < 4; ++r) Oa[r] = (hi == 0) ? csc * Fr[r] : 0.f;
        Oa = __builtin_amdgcn_mfma_f32_16x16x32_bf16(vf0, bcv(fA0), Oa, 0, 0, 0);
        Ob = __builtin_amdgcn_mfma_f32_16x16x32_bf16(vf1, bcv(fA1), Ob, 0, 0, 0);
        Oa = __builtin_amdgcn_mfma_f32_16x16x32_bf16(uf0, bcv(fB0), Oa, 0, 0, 0);
        Ob = __builtin_amdgcn_mfma_f32_16x16x32_bf16(uf1, bcv(fB1), Ob, 0, 0, 0);
        if (hi == 0) {
          float4 yo = make_float4(Vsw[0] + Oa[0] + Ob[0], Vsw[1] + Oa[1] + Ob[1],
                                  Vsw[2] + Oa[2] + Ob[2], Vsw[3] + Oa[3] + Ob[3]);
          *(float4*)(yb + (size_t)(c * CC + sidx) * DD + v0) = yo;
        }
      }
    }
    barrier_lgkm();
    // ---- phase D: S = lam64*S + Ws^T.K ----
    {
      bf16x8 ws0 = ldf(Ws + lo * 64 + ((hi * 8) ^ mLo));
      bf16x8 ws1 = ldf(Ws + lo * 64 + ((hi * 8 + 32) ^ mLo));
#pragma unroll
      for (int t = 0; t < 4; ++t) {
        f32x4 acc = Sa[t] * lam64;
        acc = __builtin_amdgcn_mfma_f32_16x16x32_bf16(ws0, bcv(kt0[t]), acc, 0, 0, 0);
        acc = __builtin_amdgcn_mfma_f32_16x16x32_bf16(ws1, bcv(kt1[t]), acc, 0, 0, 0);
        Sa[t] = acc;
      }
      if (hi == 0) {
#pragma unroll
        for (int t = 0; t < 4; ++t) {
          int kc = 16 * (4 * wid + t) + lo;
#pragma unroll
          for (int r = 0; r < 4; ++r)
            Sb[r * DD + (kc ^ (sx6(r) << 3))] = f2bf(Sa[t][r]);
        }
      }
    }
    // ---- prefetch kt/frames for c+1 ----
    if (c + 1 < NC) {
      const u16* ktc = kbt + (size_t)(b * NC + c + 1) * CC * DD;
#pragma unroll
      for (int t = 0; t < 4; ++t) {
        int k = 16 * (4 * wid + t) + lo;
        const u16* rowp = ktc + (size_t)k * 64;
        int m = sx6(k) << 3;
        kt0[t] = *(const u32x4*)(rowp + ((8 * hi) ^ m));
        kt1[t] = *(const u32x4*)(rowp + ((8 * hi + 32) ^ m));
      }
      size_t tbase = ((size_t)(b * NC + c + 1) * 64 + sidx) * 64 + hi * 8;
      const u16* mA = (kh == 0) ? tbs : p1g;
      const u16* mB = (kh == 0) ? tcs : p2g;
      fA0 = *(const u32x4*)(mA + tbase);
      fA1 = *(const u32x4*)(mA + tbase + 32);
      fB0 = *(const u32x4*)(mB + tbase);
      fB1 = *(const u32x4*)(mB + tbase + 32);
    }
    barrier_lgkm();
  }
}

// ---------------------------------------------------------------------------
// K4: LayerNorm in-place on d_out.
// ---------------------------------------------------------------------------
__global__ __launch_bounds__(256) void k_ln(float* __restrict__ y,
                                            const float* __restrict__ gamma,
                                            const float* __restrict__ lbeta) {
  int row = blockIdx.x * 4 + (threadIdx.x >> 6);
  int lane = threadIdx.x & 63;
  float* yr = y + (size_t)row * DD + lane * 8;
  float4 a = *(const float4*)yr;
  float4 b = *(const float4*)(yr + 4);
  float v[8] = {a.x, a.y, a.z, a.w, b.x, b.y, b.z, b.w};
  float s = 0.f, ss = 0.f;
#pragma unroll
  for (int j = 0; j < 8; ++j) {
    s += v[j];
    ss = fmaf(v[j], v[j], ss);
  }
#pragma unroll
  for (int m = 1; m < 64; m <<= 1) {
    s += __shfl_xor(s, m, 64);
    ss += __shfl_xor(ss, m, 64);
  }
  float mu = s * (1.f / DD);
  float var = ss * (1.f / DD) - mu * mu;
  float inv = rsqrtf(var + EPSF);
  const float* gp = gamma + lane * 8;
  const float* bp = lbeta + lane * 8;
  float4 g0 = *(const float4*)gp;
  float4 g1 = *(const float4*)(gp + 4);
  float4 b0 = *(const float4*)bp;
  float4 b1 = *(const float4*)(bp + 4);
  float g[8] = {g0.x, g0.y, g0.z, g0.w, g1.x, g1.y, g1.z, g1.w};
  float bb[8] = {b0.x, b0.y, b0.z, b0.w, b1.x, b1.y, b1.z, b1.w};
#pragma unroll
  for (int j = 0; j < 8; ++j) v[j] = (v[j] - mu) * inv * g[j] + bb[j];
  *(float4*)yr = make_float4(v[0], v[1], v[2], v[3]);
  *(float4*)(yr + 4) = make_float4(v[4], v[5], v[6], v[7]);
}

// ---------------------------------------------------------------------------
extern "C" void kernel_launch(void* const* d_in, const int* in_sizes, int n_in,
                              void* d_out, int out_size, void* d_ws, size_t ws_size,
                              hipStream_t stream) {
  const float* x     = (const float*)d_in[0];
  const float* W     = (const float*)d_in[1];
  const float* eta   = (const float*)d_in[2];
  const float* ll    = (const float*)d_in[3];
  const float* gamma = (const float*)d_in[4];
  const float* lbeta = (const float*)d_in[5];
  float* out = (float*)d_out;

  // ws (u16): kbs 8MB | kbt 8MB | wbb 0.5MB | tbs/tcs/p1/p2 1MB each (~20.5MB)
  u16* kbs = (u16*)d_ws;
  u16* kbt = kbs + (size_t)BB * LL * DD;
  u16* wbb = kbt + (size_t)BB * LL * DD;
  u16* tbs = wbb + (size_t)DD * DD;
  u16* tcs = tbs + (size_t)BB * NC * 64 * 64;
  u16* p1g = tcs + (size_t)BB * NC * 64 * 64;
  u16* p2g = p1g + (size_t)BB * NC * 64 * 64;

  k_cvtW<<<128, 256, 0, stream>>>(W, wbb);
  k_prep3<<<BB * NC, 256, 0, stream>>>(x, eta, ll, kbs, tbs, tcs, p1g, p2g, kbt);
  k_scanA<<<512, 512, 0, stream>>>(kbs, kbt, wbb, tbs, tcs, p1g, p2g, ll, out);
  k_ln<<<2048, 256, 0, stream>>>(out, gamma, lbeta);
}

// Round 12
// 230.288 us; speedup vs baseline: 2.6560x; 2.6560x over previous
//
#include <hip/hip_runtime.h>
#include <math.h>

#define BB 4
#define LL 2048
#define DD 512
#define CC 64      // chunk length
#define NC 32      // number of chunks
#define VB 4       // v-columns owned per workgroup
#define EPSF 1e-5f

typedef unsigned int u32;
typedef unsigned short u16;
typedef __attribute__((ext_vector_type(4))) u32 u32x4;
typedef __attribute__((ext_vector_type(4))) float f32x4;
typedef __attribute__((ext_vector_type(8))) __bf16 bf16x8;

__device__ __forceinline__ u16 f2bf(float f) {           // native RNE cvt
  return __builtin_bit_cast(u16, (__bf16)f);
}
__device__ __forceinline__ int sx6(int s) { return (s ^ (s >> 3)) & 7; }
__device__ __forceinline__ bf16x8 ldf(const u16* p) {
  return __builtin_bit_cast(bf16x8, *(const u32x4*)p);
}
__device__ __forceinline__ bf16x8 bcv(u32x4 v) { return __builtin_bit_cast(bf16x8, v); }

__device__ __forceinline__ void gld16(u16* lds, const u16* g) {
  __builtin_amdgcn_global_load_lds(
      (const __attribute__((address_space(1))) u32*)g,
      (__attribute__((address_space(3))) u32*)lds, 16, 0, 0);
}
// barrier that drains only LDS (keeps global loads in flight)
__device__ __forceinline__ void barrier_lgkm() {
  asm volatile("s_waitcnt lgkmcnt(0)" ::: "memory");
  __builtin_amdgcn_sched_barrier(0);
  __builtin_amdgcn_s_barrier();
  __builtin_amdgcn_sched_barrier(0);
}
__device__ __forceinline__ void barrier_all() {
  asm volatile("s_waitcnt vmcnt(0) lgkmcnt(0)" ::: "memory");
  __builtin_amdgcn_sched_barrier(0);
  __builtin_amdgcn_s_barrier();
  __builtin_amdgcn_sched_barrier(0);
}

// ---------------------------------------------------------------------------
// K1b: W -> bf16 (row-major)
// ---------------------------------------------------------------------------
__global__ __launch_bounds__(256) void k_cvtW(const float* __restrict__ W,
                                              u16* __restrict__ wbb) {
  int idx = (blockIdx.x * 256 + threadIdx.x) * 8;
  float4 a = *(const float4*)(W + idx);
  float4 b = *(const float4*)(W + idx + 4);
  float v[8] = {a.x, a.y, a.z, a.w, b.x, b.y, b.z, b.w};
  u32x4 pk;
#pragma unroll
  for (int j = 0; j < 4; ++j)
    pk[j] = (u32)f2bf(v[2 * j]) | ((u32)f2bf(v[2 * j + 1]) << 16);
  *(u32x4*)(wbb + idx) = pk;
}

// ---------------------------------------------------------------------------
// K2: fused per-(b,chunk) prep (unchanged):
//   tanh(x-chunk) -> Kl LDS + kbs global (pre-swizzled bf16 rows)
//   G = K K^T (MFMA); T = (I+A)^{-1} (fwd subst, 4 lanes/col)
//   tbs[s][r] = lam^{63-s}*beta*T ; tcs = -lam^{63-s}*beta*T*lam^{r+1}
//   p1g = Mt.(beta*T) ; p2g = Mt.(-beta*T*diag(lam^{r+1})) ; kbt = K^T swz
// ---------------------------------------------------------------------------
__global__ __launch_bounds__(256) void k_prep3(const float* __restrict__ x,
                                               const float* __restrict__ eta_p,
                                               const float* __restrict__ ll_p,
                                               u16* __restrict__ kbs,
                                               u16* __restrict__ tbs,
                                               u16* __restrict__ tcs,
                                               u16* __restrict__ p1g,
                                               u16* __restrict__ p2g,
                                               u16* __restrict__ kbt) {
  __shared__ __align__(16) u16 Kl[CC * DD];   // 64 KB
  __shared__ float Gl[64 * 64];
  __shared__ float Gs[64 * 64];
  __shared__ float Tl[64 * 65];
  __shared__ __align__(16) u16 MtL[64 * 64];
  __shared__ __align__(16) u16 TbT[64 * 64];
  __shared__ __align__(16) u16 TcT[64 * 64];
  __shared__ float pw[72];
  int bc = blockIdx.x;
  int b = bc >> 5, c = bc & 31;
  int tid = threadIdx.x;
  int wid = tid >> 6, lane = tid & 63;
  int lo = lane & 15, hi = lane >> 4;
  float beta = *eta_p;
  float lam = 1.f / (1.f + expf(-*ll_p));
  if (tid <= 64) pw[tid] = powf(lam, (float)tid);
  for (int i = tid; i < 64 * 65; i += 256) Tl[i] = 0.f;
  // ---- tanh + pack ----
  const float* xg = x + (size_t)(b * LL + c * CC) * DD;
  u16* kbs_c = kbs + (size_t)(b * LL + c * CC) * DD;
#pragma unroll
  for (int i = 0; i < 16; ++i) {
    int idx = tid + i * 256;
    int r = idx >> 6, k8 = (idx & 63) * 8;
    const float* xp = xg + (size_t)r * DD + k8;
    float4 a = *(const float4*)xp;
    float4 b4 = *(const float4*)(xp + 4);
    float v[8] = {a.x, a.y, a.z, a.w, b4.x, b4.y, b4.z, b4.w};
    u32x4 pk;
#pragma unroll
    for (int j = 0; j < 4; ++j)
      pk[j] = (u32)f2bf(tanhf(v[2 * j])) | ((u32)f2bf(tanhf(v[2 * j + 1])) << 16);
    int off = r * DD + (k8 ^ (sx6(r) << 3));
    *(u32x4*)(Kl + off) = pk;
    *(u32x4*)(kbs_c + off) = pk;
  }
  __syncthreads();
  // ---- G = K K^T ----
  {
    f32x4 acc[4] = {{0.f,0.f,0.f,0.f},{0.f,0.f,0.f,0.f},{0.f,0.f,0.f,0.f},{0.f,0.f,0.f,0.f}};
    int t = 16 * wid + lo;
    int mT = sx6(t) << 3;
#pragma unroll
    for (int kq = 0; kq < 16; ++kq) {
      int col = hi * 8 + kq * 32;
      bf16x8 aF = ldf(Kl + t * DD + (col ^ mT));
#pragma unroll
      for (int sb = 0; sb < 4; ++sb) {
        int s = 16 * sb + lo;
        bf16x8 bF = ldf(Kl + s * DD + (col ^ (sx6(s) << 3)));
        acc[sb] = __builtin_amdgcn_mfma_f32_16x16x32_bf16(aF, bF, acc[sb], 0, 0, 0);
      }
    }
#pragma unroll
    for (int sb = 0; sb < 4; ++sb)
#pragma unroll
      for (int r = 0; r < 4; ++r)
        Gl[(16 * wid + 4 * hi + r) * 64 + 16 * sb + lo] = acc[sb][r];
  }
  __syncthreads();
#pragma unroll
  for (int i = 0; i < 16; ++i) {
    int idx = tid + i * 256;
    int tq = idx >> 6, sq = idx & 63;
    Gs[idx] = (sq < tq) ? beta * pw[tq - sq] * Gl[idx] : 0.f;
  }
  __syncthreads();
  // ---- forward substitution ----
  {
    int q = hi;
    int j = 16 * wid + lo;
    for (int t = 0; t < 64; ++t) {
      float ps = 0.f;
#pragma unroll
      for (int i = 0; i < 16; ++i) {
        int s = 16 * q + i;
        ps = fmaf(Gs[t * 64 + s], Tl[s * 65 + j], ps);
      }
      ps += __shfl_xor(ps, 16, 64);
      ps += __shfl_xor(ps, 32, 64);
      if (q == 0) Tl[t * 65 + j] = ((t == j) ? 1.f : 0.f) - ps;
    }
  }
  __syncthreads();
  // ---- tbs/tcs + LDS tiles for P GEMMs ----
  u16* tbso = tbs + (size_t)bc * 4096;
  u16* tcso = tcs + (size_t)bc * 4096;
#pragma unroll
  for (int i = 0; i < 16; ++i) {
    int idx = tid + i * 256;
    int s = idx >> 6, r = idx & 63;
    float tv = Tl[s * 65 + r];
    float sc = pw[63 - s] * beta;
    tbso[idx] = f2bf(sc * tv);
    tcso[idx] = f2bf(-sc * pw[r + 1] * tv);
    int swz = r ^ (sx6(s) << 3);
    float mtv = (r < s) ? pw[s - r] * Gl[s * 64 + r]
                        : ((r == s) ? Gl[s * 64 + r] : 0.f);
    MtL[s * 64 + swz] = f2bf(mtv);
    float tvT = Tl[r * 65 + s];
    TbT[s * 64 + swz] = f2bf(beta * tvT);
    TcT[s * 64 + swz] = f2bf(-beta * pw[s + 1] * tvT);
  }
  __syncthreads();
  // ---- P1 = Mt.Tb, P2 = Mt.Tc ----
  {
    f32x4 p1a[4], p2a[4];
#pragma unroll
    for (int rt = 0; rt < 4; ++rt) {
      p1a[rt] = (f32x4){0.f, 0.f, 0.f, 0.f};
      p2a[rt] = (f32x4){0.f, 0.f, 0.f, 0.f};
    }
    int srow = 16 * wid + lo;
    int aswz = sx6(srow) << 3;
#pragma unroll
    for (int km = 0; km < 2; ++km) {
      int mo = hi * 8 + km * 32;
      bf16x8 aF = ldf(MtL + srow * 64 + (mo ^ aswz));
#pragma unroll
      for (int rt = 0; rt < 4; ++rt) {
        int rrow = 16 * rt + lo;
        int bswz = sx6(rrow) << 3;
        p1a[rt] = __builtin_amdgcn_mfma_f32_16x16x32_bf16(
            aF, ldf(TbT + rrow * 64 + (mo ^ bswz)), p1a[rt], 0, 0, 0);
        p2a[rt] = __builtin_amdgcn_mfma_f32_16x16x32_bf16(
            aF, ldf(TcT + rrow * 64 + (mo ^ bswz)), p2a[rt], 0, 0, 0);
      }
    }
    u16* p1o = p1g + (size_t)bc * 4096;
    u16* p2o = p2g + (size_t)bc * 4096;
#pragma unroll
    for (int rt = 0; rt < 4; ++rt)
#pragma unroll
      for (int rg = 0; rg < 4; ++rg) {
        int s = 16 * wid + 4 * hi + rg;
        int r = 16 * rt + lo;
        p1o[s * 64 + r] = f2bf(p1a[rt][rg]);
        p2o[s * 64 + r] = f2bf(p2a[rt][rg]);
      }
  }
  // ---- kbt = K^T, swizzled ----
  u16* ktb = kbt + (size_t)bc * CC * DD;
#pragma unroll
  for (int rr = 0; rr < 2; ++rr) {
    int k = rr * 256 + tid;
    int kbase = k & ~7, klo = k & 7;
    int mk = sx6(k) << 3;
#pragma unroll
    for (int g = 0; g < 8; ++g) {
      u32 w4[4];
#pragma unroll
      for (int p = 0; p < 4; ++p) {
        int s0 = g * 8 + 2 * p;
        u16 e0 = Kl[s0 * DD + (kbase ^ (sx6(s0) << 3)) + klo];
        u16 e1 = Kl[(s0 + 1) * DD + (kbase ^ (sx6(s0 + 1) << 3)) + klo];
        w4[p] = (u32)e0 | ((u32)e1 << 16);
      }
      *(u32x4*)(ktb + (size_t)k * 64 + ((8 * g) ^ mk)) = (u32x4){w4[0], w4[1], w4[2], w4[3]};
    }
  }
}

// ---------------------------------------------------------------------------
// K3: MFMA chunked scan vB. VB=4, 512 WGs; __launch_bounds__(512,2) so the
//   compiler keeps ~108 VGPR (no spills); HW co-schedules 2 WGs/CU
//   (LDS 2x28.7KB, VGPR<=128) -> 4 waves/SIMD via independent WGs.
//   M-dim packing: rows 0-3 = S^T, rows 4-7 = W, rows 8-15 = zero.
//   Schedule: UV(8) -> bar -> reduce (+kB prefetch) -> bar ->
//             B(kh0) || C+y(kh1) -> bar -> D(8) (+prefetch) -> bar
// ---------------------------------------------------------------------------
__global__ __launch_bounds__(512, 2) void k_scanB(const u16* __restrict__ kbs,
                                                  const u16* __restrict__ kbt,
                                                  const u16* __restrict__ wbb,
                                                  const u16* __restrict__ tbs,
                                                  const u16* __restrict__ tcs,
                                                  const u16* __restrict__ p1g,
                                                  const u16* __restrict__ p2g,
                                                  const float* __restrict__ ll_p,
                                                  float* __restrict__ y) {
  __shared__ __align__(16) u16 Sb[16 * DD];       // rows0-3 S, 4-7 W, 8-15 zero
  __shared__ __align__(16) float Up[2][64][12];   // fp32 partials [kh][s][m0-7]
  __shared__ __align__(16) u16 Vt[16 * 64];
  __shared__ __align__(16) u16 Ut[16 * 64];
  __shared__ __align__(16) u16 Ws[16 * 64];

  int b = blockIdx.x >> 7;
  int vb = blockIdx.x & 127;
  int v0 = vb * VB;
  int tid = threadIdx.x;
  int wid = tid >> 6, lane = tid & 63;
  int wq = wid & 3, kh = wid >> 2;
  int lo = lane & 15, hi = lane >> 4;
  int sidx = 16 * wq + lo;
  int mS = sx6(sidx) << 3;     // swizzle for kbs row sidx
  int mLo = sx6(lo) << 3;      // swizzle for LDS row lo
  int kOff = kh * 256;

  float lam = 1.f / (1.f + expf(-*ll_p));
  float lam64 = powf(lam, 64.f);
  float csc = powf(lam, (float)(sidx + 1));

  // ---- init LDS ----
  {
    u32x4 z = {0u, 0u, 0u, 0u};
    if (tid < 256) *((u32x4*)Sb + tid) = z;        // rows 0-3
    *((u32x4*)Sb + 512 + tid) = z;                 // rows 8-15
    if (tid < 384) {
      u16* base = (tid >> 7) == 0 ? Vt : (tid >> 7) == 1 ? Ut : Ws;
      *((u32x4*)base + (tid & 127)) = z;
    }
    if (wid < 4) {  // W rows v0..v0+3 into Sb rows 4..7
      u32x4 wrow = *(const u32x4*)(wbb + (size_t)(v0 + wid) * DD + lane * 8);
      *(u32x4*)(Sb + (size_t)(4 + wid) * DD + ((lane * 8) ^ (sx6(4 + wid) << 3))) = wrow;
    }
  }
  const u16* kb_b = kbs + (size_t)b * LL * DD;
  float* yb = y + (size_t)b * LL * DD;

  // ---- prologue global loads: kB chunk0, kt chunk0, frames chunk0 ----
  u32x4 kB[8];
#pragma unroll
  for (int kq = 0; kq < 8; ++kq)
    kB[kq] = *(const u32x4*)(kb_b + (size_t)sidx * DD +
                             ((kOff + hi * 8 + kq * 32) ^ mS));
  u32x4 kt0[4], kt1[4], fA0, fA1, fB0, fB1;
  {
    const u16* ktc = kbt + (size_t)(b * NC + 0) * CC * DD;
#pragma unroll
    for (int t = 0; t < 4; ++t) {
      int k = 16 * (4 * wid + t) + lo;
      const u16* rowp = ktc + (size_t)k * 64;
      int m = sx6(k) << 3;
      kt0[t] = *(const u32x4*)(rowp + ((8 * hi) ^ m));
      kt1[t] = *(const u32x4*)(rowp + ((8 * hi + 32) ^ m));
    }
    size_t tbase = ((size_t)(b * NC + 0) * 64 + sidx) * 64 + hi * 8;
    const u16* mA = (kh == 0) ? tbs : p1g;
    const u16* mB = (kh == 0) ? tcs : p2g;
    fA0 = *(const u32x4*)(mA + tbase);
    fA1 = *(const u32x4*)(mA + tbase + 32);
    fB0 = *(const u32x4*)(mB + tbase);
    fB1 = *(const u32x4*)(mB + tbase + 32);
  }
  f32x4 Sa[4];
#pragma unroll
  for (int t = 0; t < 4; ++t) Sa[t] = (f32x4){0.f, 0.f, 0.f, 0.f};
  barrier_all();

  for (int c = 0; c < NC; ++c) {
    // ---- phase UV: [U;V] partials, K from regs ----
    {
      f32x4 A0 = {0.f,0.f,0.f,0.f}, A1 = {0.f,0.f,0.f,0.f};
#pragma unroll
      for (int kq = 0; kq < 8; ++kq) {
        int col = kOff + hi * 8 + kq * 32;
        bf16x8 sA = ldf(Sb + lo * DD + (col ^ mLo));
        if (kq & 1) A1 = __builtin_amdgcn_mfma_f32_16x16x32_bf16(sA, bcv(kB[kq]), A1, 0, 0, 0);
        else        A0 = __builtin_amdgcn_mfma_f32_16x16x32_bf16(sA, bcv(kB[kq]), A0, 0, 0, 0);
      }
      f32x4 F = A0 + A1;
      if (hi < 2) *(f32x4*)&Up[kh][sidx][4 * hi] = F;
    }
    barrier_lgkm();
    // ---- prefetch kB for c+1 (regs free after UV) ----
    if (c + 1 < NC) {
      const u16* src = kb_b + ((size_t)(c + 1) * CC + sidx) * DD;
#pragma unroll
      for (int kq = 0; kq < 8; ++kq)
        kB[kq] = *(const u32x4*)(src + ((kOff + hi * 8 + kq * 32) ^ mS));
    }
    // ---- reduce k-halves: hi=0 -> U rows 0-3, hi=1 -> V rows 0-3 ----
    f32x4 Fr = {0.f, 0.f, 0.f, 0.f};
    if (hi < 2) {
      f32x4 a = *(const f32x4*)&Up[0][sidx][4 * hi];
      f32x4 bq = *(const f32x4*)&Up[1][sidx][4 * hi];
      Fr = a + bq;
      if (kh == 0) {
        if (hi == 0) {
#pragma unroll
          for (int r = 0; r < 4; ++r)
            Ut[r * 64 + (sidx ^ (sx6(r) << 3))] = f2bf(Fr[r]);
        } else {
#pragma unroll
          for (int r = 0; r < 4; ++r)
            Vt[r * 64 + (sidx ^ (sx6(r) << 3))] = f2bf(Fr[r]);
        }
      }
    }
    barrier_lgkm();
    // ---- B (kh0) || C+y (kh1) ----
    {
      bf16x8 vf0 = ldf(Vt + lo * 64 + ((hi * 8) ^ mLo));
      bf16x8 vf1 = ldf(Vt + lo * 64 + ((hi * 8 + 32) ^ mLo));
      bf16x8 uf0 = ldf(Ut + lo * 64 + ((hi * 8) ^ mLo));
      bf16x8 uf1 = ldf(Ut + lo * 64 + ((hi * 8 + 32) ^ mLo));
      if (kh == 0) {
        f32x4 Wa0 = {0.f,0.f,0.f,0.f}, Wa1 = {0.f,0.f,0.f,0.f};
        Wa0 = __builtin_amdgcn_mfma_f32_16x16x32_bf16(vf0, bcv(fA0), Wa0, 0, 0, 0);
        Wa1 = __builtin_amdgcn_mfma_f32_16x16x32_bf16(vf1, bcv(fA1), Wa1, 0, 0, 0);
        Wa0 = __builtin_amdgcn_mfma_f32_16x16x32_bf16(uf0, bcv(fB0), Wa0, 0, 0, 0);
        Wa1 = __builtin_amdgcn_mfma_f32_16x16x32_bf16(uf1, bcv(fB1), Wa1, 0, 0, 0);
        f32x4 Wa = Wa0 + Wa1;
        if (hi == 0) {
#pragma unroll
          for (int r = 0; r < 4; ++r)
            Ws[r * 64 + (sidx ^ (sx6(r) << 3))] = f2bf(Wa[r]);
        }
      } else {
        // V lives in hi=1 lanes' Fr; bring to hi=0 via lane^16
        f32x4 Vsw;
#pragma unroll
        for (int r = 0; r < 4; ++r) Vsw[r] = __shfl_xor(Fr[r], 16, 64);
        f32x4 Oa, Ob = {0.f,0.f,0.f,0.f};
#pragma unroll
        for (int r = 0; r < 4; ++r) Oa[r] = (hi == 0) ? csc * Fr[r] : 0.f;
        Oa = __builtin_amdgcn_mfma_f32_16x16x32_bf16(vf0, bcv(fA0), Oa, 0, 0, 0);
        Ob = __builtin_amdgcn_mfma_f32_16x16x32_bf16(vf1, bcv(fA1), Ob, 0, 0, 0);
        Oa = __builtin_amdgcn_mfma_f32_16x16x32_bf16(uf0, bcv(fB0), Oa, 0, 0, 0);
        Ob = __builtin_amdgcn_mfma_f32_16x16x32_bf16(uf1, bcv(fB1), Ob, 0, 0, 0);
        if (hi == 0) {
          float4 yo = make_float4(Vsw[0] + Oa[0] + Ob[0], Vsw[1] + Oa[1] + Ob[1],
                                  Vsw[2] + Oa[2] + Ob[2], Vsw[3] + Oa[3] + Ob[3]);
          *(float4*)(yb + (size_t)(c * CC + sidx) * DD + v0) = yo;
        }
      }
    }
    barrier_lgkm();
    // ---- phase D: S = lam64*S + Ws^T.K ----
    {
      bf16x8 ws0 = ldf(Ws + lo * 64 + ((hi * 8) ^ mLo));
      bf16x8 ws1 = ldf(Ws + lo * 64 + ((hi * 8 + 32) ^ mLo));
#pragma unroll
      for (int t = 0; t < 4; ++t) {
        f32x4 acc = Sa[t] * lam64;
        acc = __builtin_amdgcn_mfma_f32_16x16x32_bf16(ws0, bcv(kt0[t]), acc, 0, 0, 0);
        acc = __builtin_amdgcn_mfma_f32_16x16x32_bf16(ws1, bcv(kt1[t]), acc, 0, 0, 0);
        Sa[t] = acc;
      }
      if (hi == 0) {
#pragma unroll
        for (int t = 0; t < 4; ++t) {
          int kc = 16 * (4 * wid + t) + lo;
#pragma unroll
          for (int r = 0; r < 4; ++r)
            Sb[r * DD + (kc ^ (sx6(r) << 3))] = f2bf(Sa[t][r]);
        }
      }
    }
    // ---- prefetch kt/frames for c+1 ----
    if (c + 1 < NC) {
      const u16* ktc = kbt + (size_t)(b * NC + c + 1) * CC * DD;
#pragma unroll
      for (int t = 0; t < 4; ++t) {
        int k = 16 * (4 * wid + t) + lo;
        const u16* rowp = ktc + (size_t)k * 64;
        int m = sx6(k) << 3;
        kt0[t] = *(const u32x4*)(rowp + ((8 * hi) ^ m));
        kt1[t] = *(const u32x4*)(rowp + ((8 * hi + 32) ^ m));
      }
      size_t tbase = ((size_t)(b * NC + c + 1) * 64 + sidx) * 64 + hi * 8;
      const u16* mA = (kh == 0) ? tbs : p1g;
      const u16* mB = (kh == 0) ? tcs : p2g;
      fA0 = *(const u32x4*)(mA + tbase);
      fA1 = *(const u32x4*)(mA + tbase + 32);
      fB0 = *(const u32x4*)(mB + tbase);
      fB1 = *(const u32x4*)(mB + tbase + 32);
    }
    barrier_lgkm();
  }
}

// ---------------------------------------------------------------------------
// K4: LayerNorm in-place on d_out.
// ---------------------------------------------------------------------------
__global__ __launch_bounds__(256) void k_ln(float* __restrict__ y,
                                            const float* __restrict__ gamma,
                                            const float* __restrict__ lbeta) {
  int row = blockIdx.x * 4 + (threadIdx.x >> 6);
  int lane = threadIdx.x & 63;
  float* yr = y + (size_t)row * DD + lane * 8;
  float4 a = *(const float4*)yr;
  float4 b = *(const float4*)(yr + 4);
  float v[8] = {a.x, a.y, a.z, a.w, b.x, b.y, b.z, b.w};
  float s = 0.f, ss = 0.f;
#pragma unroll
  for (int j = 0; j < 8; ++j) {
    s += v[j];
    ss = fmaf(v[j], v[j], ss);
  }
#pragma unroll
  for (int m = 1; m < 64; m <<= 1) {
    s += __shfl_xor(s, m, 64);
    ss += __shfl_xor(ss, m, 64);
  }
  float mu = s * (1.f / DD);
  float var = ss * (1.f / DD) - mu * mu;
  float inv = rsqrtf(var + EPSF);
  const float* gp = gamma + lane * 8;
  const float* bp = lbeta + lane * 8;
  float4 g0 = *(const float4*)gp;
  float4 g1 = *(const float4*)(gp + 4);
  float4 b0 = *(const float4*)bp;
  float4 b1 = *(const float4*)(bp + 4);
  float g[8] = {g0.x, g0.y, g0.z, g0.w, g1.x, g1.y, g1.z, g1.w};
  float bb[8] = {b0.x, b0.y, b0.z, b0.w, b1.x, b1.y, b1.z, b1.w};
#pragma unroll
  for (int j = 0; j < 8; ++j) v[j] = (v[j] - mu) * inv * g[j] + bb[j];
  *(float4*)yr = make_float4(v[0], v[1], v[2], v[3]);
  *(float4*)(yr + 4) = make_float4(v[4], v[5], v[6], v[7]);
}

// ---------------------------------------------------------------------------
extern "C" void kernel_launch(void* const* d_in, const int* in_sizes, int n_in,
                              void* d_out, int out_size, void* d_ws, size_t ws_size,
                              hipStream_t stream) {
  const float* x     = (const float*)d_in[0];
  const float* W     = (const float*)d_in[1];
  const float* eta   = (const float*)d_in[2];
  const float* ll    = (const float*)d_in[3];
  const float* gamma = (const float*)d_in[4];
  const float* lbeta = (const float*)d_in[5];
  float* out = (float*)d_out;

  // ws (u16): kbs 8MB | kbt 8MB | wbb 0.5MB | tbs/tcs/p1/p2 1MB each (~20.5MB)
  u16* kbs = (u16*)d_ws;
  u16* kbt = kbs + (size_t)BB * LL * DD;
  u16* wbb = kbt + (size_t)BB * LL * DD;
  u16* tbs = wbb + (size_t)DD * DD;
  u16* tcs = tbs + (size_t)BB * NC * 64 * 64;
  u16* p1g = tcs + (size_t)BB * NC * 64 * 64;
  u16* p2g = p1g + (size_t)BB * NC * 64 * 64;

  k_cvtW<<<128, 256, 0, stream>>>(W, wbb);
  k_prep3<<<BB * NC, 256, 0, stream>>>(x, eta, ll, kbs, tbs, tcs, p1g, p2g, kbt);
  k_scanB<<<512, 512, 0, stream>>>(kbs, kbt, wbb, tbs, tcs, p1g, p2g, ll, out);
  k_ln<<<2048, 256, 0, stream>>>(out, gamma, lbeta);
}

// Round 13
// 146.384 us; speedup vs baseline: 4.1783x; 1.5732x over previous
//
#include <hip/hip_runtime.h>
#include <math.h>

#define BB 4
#define LL 2048
#define DD 512
#define CC 64      // chunk length
#define NC 32      // number of chunks
#define VB 8       // v-columns owned per workgroup
#define EPSF 1e-5f

typedef unsigned int u32;
typedef unsigned short u16;
typedef __attribute__((ext_vector_type(4))) u32 u32x4;
typedef __attribute__((ext_vector_type(4))) float f32x4;
typedef __attribute__((ext_vector_type(8))) __bf16 bf16x8;

__device__ __forceinline__ u16 f2bf(float f) {           // native RNE cvt
  return __builtin_bit_cast(u16, (__bf16)f);
}
__device__ __forceinline__ int sx6(int s) { return (s ^ (s >> 3)) & 7; }
__device__ __forceinline__ bf16x8 ldf(const u16* p) {
  return __builtin_bit_cast(bf16x8, *(const u32x4*)p);
}
__device__ __forceinline__ bf16x8 bcv(u32x4 v) { return __builtin_bit_cast(bf16x8, v); }

__device__ __forceinline__ void gld16(u16* lds, const u16* g) {
  __builtin_amdgcn_global_load_lds(
      (const __attribute__((address_space(1))) u32*)g,
      (__attribute__((address_space(3))) u32*)lds, 16, 0, 0);
}
// barrier that drains only LDS (keeps global loads in flight)
__device__ __forceinline__ void barrier_lgkm() {
  asm volatile("s_waitcnt lgkmcnt(0)" ::: "memory");
  __builtin_amdgcn_sched_barrier(0);
  __builtin_amdgcn_s_barrier();
  __builtin_amdgcn_sched_barrier(0);
}
__device__ __forceinline__ void barrier_all() {
  asm volatile("s_waitcnt vmcnt(0) lgkmcnt(0)" ::: "memory");
  __builtin_amdgcn_sched_barrier(0);
  __builtin_amdgcn_s_barrier();
  __builtin_amdgcn_sched_barrier(0);
}

// ---------------------------------------------------------------------------
// K1b: W -> bf16 (row-major)
// ---------------------------------------------------------------------------
__global__ __launch_bounds__(256) void k_cvtW(const float* __restrict__ W,
                                              u16* __restrict__ wbb) {
  int idx = (blockIdx.x * 256 + threadIdx.x) * 8;
  float4 a = *(const float4*)(W + idx);
  float4 b = *(const float4*)(W + idx + 4);
  float v[8] = {a.x, a.y, a.z, a.w, b.x, b.y, b.z, b.w};
  u32x4 pk;
#pragma unroll
  for (int j = 0; j < 4; ++j)
    pk[j] = (u32)f2bf(v[2 * j]) | ((u32)f2bf(v[2 * j + 1]) << 16);
  *(u32x4*)(wbb + idx) = pk;
}

// ---------------------------------------------------------------------------
// K2: fused per-(b,chunk) prep:
//   tanh(x-chunk) -> Kl LDS + kbs global (pre-swizzled bf16 rows)
//   G = K K^T (MFMA); T = (I+A)^{-1} (fwd subst, 4 lanes/col)
//   tbs[s][r] = lam^{63-s}*beta*T ; tcs = -lam^{63-s}*beta*T*lam^{r+1}
//   p1g = Mt.(beta*T) + I ; p2g = Mt.(-beta*T*diag(lam^{r+1})) + diag(lam^{s+1})
//   kbt = K^T swz
// ---------------------------------------------------------------------------
__global__ __launch_bounds__(256) void k_prep3(const float* __restrict__ x,
                                               const float* __restrict__ eta_p,
                                               const float* __restrict__ ll_p,
                                               u16* __restrict__ kbs,
                                               u16* __restrict__ tbs,
                                               u16* __restrict__ tcs,
                                               u16* __restrict__ p1g,
                                               u16* __restrict__ p2g,
                                               u16* __restrict__ kbt) {
  __shared__ __align__(16) u16 Kl[CC * DD];   // 64 KB
  __shared__ float Gl[64 * 64];
  __shared__ float Gs[64 * 64];
  __shared__ float Tl[64 * 65];
  __shared__ __align__(16) u16 MtL[64 * 64];
  __shared__ __align__(16) u16 TbT[64 * 64];
  __shared__ __align__(16) u16 TcT[64 * 64];
  __shared__ float pw[72];
  int bc = blockIdx.x;
  int b = bc >> 5, c = bc & 31;
  int tid = threadIdx.x;
  int wid = tid >> 6, lane = tid & 63;
  int lo = lane & 15, hi = lane >> 4;
  float beta = *eta_p;
  float lam = 1.f / (1.f + expf(-*ll_p));
  if (tid <= 64) pw[tid] = powf(lam, (float)tid);
  for (int i = tid; i < 64 * 65; i += 256) Tl[i] = 0.f;
  // ---- tanh + pack ----
  const float* xg = x + (size_t)(b * LL + c * CC) * DD;
  u16* kbs_c = kbs + (size_t)(b * LL + c * CC) * DD;
#pragma unroll
  for (int i = 0; i < 16; ++i) {
    int idx = tid + i * 256;
    int r = idx >> 6, k8 = (idx & 63) * 8;
    const float* xp = xg + (size_t)r * DD + k8;
    float4 a = *(const float4*)xp;
    float4 b4 = *(const float4*)(xp + 4);
    float v[8] = {a.x, a.y, a.z, a.w, b4.x, b4.y, b4.z, b4.w};
    u32x4 pk;
#pragma unroll
    for (int j = 0; j < 4; ++j)
      pk[j] = (u32)f2bf(tanhf(v[2 * j])) | ((u32)f2bf(tanhf(v[2 * j + 1])) << 16);
    int off = r * DD + (k8 ^ (sx6(r) << 3));
    *(u32x4*)(Kl + off) = pk;
    *(u32x4*)(kbs_c + off) = pk;
  }
  __syncthreads();
  // ---- G = K K^T ----
  {
    f32x4 acc[4] = {{0.f,0.f,0.f,0.f},{0.f,0.f,0.f,0.f},{0.f,0.f,0.f,0.f},{0.f,0.f,0.f,0.f}};
    int t = 16 * wid + lo;
    int mT = sx6(t) << 3;
#pragma unroll
    for (int kq = 0; kq < 16; ++kq) {
      int col = hi * 8 + kq * 32;
      bf16x8 aF = ldf(Kl + t * DD + (col ^ mT));
#pragma unroll
      for (int sb = 0; sb < 4; ++sb) {
        int s = 16 * sb + lo;
        bf16x8 bF = ldf(Kl + s * DD + (col ^ (sx6(s) << 3)));
        acc[sb] = __builtin_amdgcn_mfma_f32_16x16x32_bf16(aF, bF, acc[sb], 0, 0, 0);
      }
    }
#pragma unroll
    for (int sb = 0; sb < 4; ++sb)
#pragma unroll
      for (int r = 0; r < 4; ++r)
        Gl[(16 * wid + 4 * hi + r) * 64 + 16 * sb + lo] = acc[sb][r];
  }
  __syncthreads();
#pragma unroll
  for (int i = 0; i < 16; ++i) {
    int idx = tid + i * 256;
    int tq = idx >> 6, sq = idx & 63;
    Gs[idx] = (sq < tq) ? beta * pw[tq - sq] * Gl[idx] : 0.f;
  }
  __syncthreads();
  // ---- forward substitution ----
  {
    int q = hi;
    int j = 16 * wid + lo;
    for (int t = 0; t < 64; ++t) {
      float ps = 0.f;
#pragma unroll
      for (int i = 0; i < 16; ++i) {
        int s = 16 * q + i;
        ps = fmaf(Gs[t * 64 + s], Tl[s * 65 + j], ps);
      }
      ps += __shfl_xor(ps, 16, 64);
      ps += __shfl_xor(ps, 32, 64);
      if (q == 0) Tl[t * 65 + j] = ((t == j) ? 1.f : 0.f) - ps;
    }
  }
  __syncthreads();
  // ---- tbs/tcs + LDS tiles for P GEMMs ----
  u16* tbso = tbs + (size_t)bc * 4096;
  u16* tcso = tcs + (size_t)bc * 4096;
#pragma unroll
  for (int i = 0; i < 16; ++i) {
    int idx = tid + i * 256;
    int s = idx >> 6, r = idx & 63;
    float tv = Tl[s * 65 + r];
    float sc = pw[63 - s] * beta;
    tbso[idx] = f2bf(sc * tv);
    tcso[idx] = f2bf(-sc * pw[r + 1] * tv);
    int swz = r ^ (sx6(s) << 3);
    float mtv = (r < s) ? pw[s - r] * Gl[s * 64 + r]
                        : ((r == s) ? Gl[s * 64 + r] : 0.f);
    MtL[s * 64 + swz] = f2bf(mtv);
    float tvT = Tl[r * 65 + s];
    TbT[s * 64 + swz] = f2bf(beta * tvT);
    TcT[s * 64 + swz] = f2bf(-beta * pw[s + 1] * tvT);
  }
  __syncthreads();
  // ---- P1 = Mt.Tb + I, P2 = Mt.Tc + diag(lam^{s+1}) ----
  {
    f32x4 p1a[4], p2a[4];
#pragma unroll
    for (int rt = 0; rt < 4; ++rt) {
      p1a[rt] = (f32x4){0.f, 0.f, 0.f, 0.f};
      p2a[rt] = (f32x4){0.f, 0.f, 0.f, 0.f};
    }
    int srow = 16 * wid + lo;
    int aswz = sx6(srow) << 3;
#pragma unroll
    for (int km = 0; km < 2; ++km) {
      int mo = hi * 8 + km * 32;
      bf16x8 aF = ldf(MtL + srow * 64 + (mo ^ aswz));
#pragma unroll
      for (int rt = 0; rt < 4; ++rt) {
        int rrow = 16 * rt + lo;
        int bswz = sx6(rrow) << 3;
        p1a[rt] = __builtin_amdgcn_mfma_f32_16x16x32_bf16(
            aF, ldf(TbT + rrow * 64 + (mo ^ bswz)), p1a[rt], 0, 0, 0);
        p2a[rt] = __builtin_amdgcn_mfma_f32_16x16x32_bf16(
            aF, ldf(TcT + rrow * 64 + (mo ^ bswz)), p2a[rt], 0, 0, 0);
      }
    }
    u16* p1o = p1g + (size_t)bc * 4096;
    u16* p2o = p2g + (size_t)bc * 4096;
#pragma unroll
    for (int rt = 0; rt < 4; ++rt)
#pragma unroll
      for (int rg = 0; rg < 4; ++rg) {
        int s = 16 * wid + 4 * hi + rg;
        int r = 16 * rt + lo;
        float d1 = (s == r) ? 1.f : 0.f;
        float d2 = (s == r) ? pw[s + 1] : 0.f;
        p1o[s * 64 + r] = f2bf(p1a[rt][rg] + d1);
        p2o[s * 64 + r] = f2bf(p2a[rt][rg] + d2);
      }
  }
  // ---- kbt = K^T, swizzled ----
  u16* ktb = kbt + (size_t)bc * CC * DD;
#pragma unroll
  for (int rr = 0; rr < 2; ++rr) {
    int k = rr * 256 + tid;
    int kbase = k & ~7, klo = k & 7;
    int mk = sx6(k) << 3;
#pragma unroll
    for (int g = 0; g < 8; ++g) {
      u32 w4[4];
#pragma unroll
      for (int p = 0; p < 4; ++p) {
        int s0 = g * 8 + 2 * p;
        u16 e0 = Kl[s0 * DD + (kbase ^ (sx6(s0) << 3)) + klo];
        u16 e1 = Kl[(s0 + 1) * DD + (kbase ^ (sx6(s0 + 1) << 3)) + klo];
        w4[p] = (u32)e0 | ((u32)e1 << 16);
      }
      *(u32x4*)(ktb + (size_t)k * 64 + ((8 * g) ^ mk)) = (u32x4){w4[0], w4[1], w4[2], w4[3]};
    }
  }
}

// ---------------------------------------------------------------------------
// K3: MFMA chunked scan vC. VB=8, 256 WGs, 8 waves (wq x kh), 2 waves/SIMD.
//   3 phases / 3 barriers per chunk:
//   UV(8 mfma, acc -> bf16 per-kh tiles) -> bar ->
//   B(kh0: Ws = Tbs.V + Tcs.U over K=128) || C(kh1: y = P1'.V + P2'.U) -> bar ->
//   D(8 mfma) + prefetch -> bar
//   Reduction of k-halves folded into the K=128 MFMA (linearity); diag terms
//   folded into P1/P2 by prep (y emitted directly by C).
// ---------------------------------------------------------------------------
__global__ __launch_bounds__(512, 2) void k_scanC(const u16* __restrict__ kbs,
                                                  const u16* __restrict__ kbt,
                                                  const u16* __restrict__ wbb,
                                                  const u16* __restrict__ tbs,
                                                  const u16* __restrict__ tcs,
                                                  const u16* __restrict__ p1g,
                                                  const u16* __restrict__ p2g,
                                                  const float* __restrict__ ll_p,
                                                  float* __restrict__ y) {
  __shared__ __align__(16) u16 Sb[16 * DD];     // rows0-7 S^T, rows8-15 W
  __shared__ __align__(16) u16 Ut2[2][16 * 64]; // per-kh U^T tiles (rows 0-7)
  __shared__ __align__(16) u16 Vt2[2][16 * 64]; // per-kh V^T tiles (rows 0-7)
  __shared__ __align__(16) u16 Ws[16 * 64];

  int b = blockIdx.x >> 6;
  int vb = blockIdx.x & 63;
  int v0 = vb * VB;
  int tid = threadIdx.x;
  int wid = tid >> 6, lane = tid & 63;
  int wq = wid & 3, kh = wid >> 2;
  int lo = lane & 15, hi = lane >> 4;
  int sidx = 16 * wq + lo;
  int mS = sx6(sidx) << 3;     // swizzle for kbs row sidx
  int mLo = sx6(lo) << 3;      // swizzle for LDS row lo
  int kOff = kh * 256;

  float lam = 1.f / (1.f + expf(-*ll_p));
  float lam64 = powf(lam, 64.f);

  // ---- init LDS ----
  {
    u32x4 z = {0u, 0u, 0u, 0u};
    ((u32x4*)Sb)[tid] = z;                         // rows 0-7 (8 KB)
    if (tid < 256) {
      ((u32x4*)Ut2)[tid] = z;
      ((u32x4*)Vt2)[tid] = z;
    }
    if (tid < 128) ((u32x4*)Ws)[tid] = z;
    if (wid < 8 && wid >= 0) {}                    // (keep wid live)
    if (wid < 8) {
      // W rows v0..v0+7 into Sb rows 8..15
      u32x4 wrow = *(const u32x4*)(wbb + (size_t)(v0 + wid) * DD + lane * 8);
      *(u32x4*)(Sb + (size_t)(8 + wid) * DD + ((lane * 8) ^ (sx6(8 + wid) << 3))) = wrow;
    }
  }
  const u16* kb_b = kbs + (size_t)b * LL * DD;
  float* yb = y + (size_t)b * LL * DD;

  // ---- prologue global loads: kB chunk0, kt chunk0, frames chunk0 ----
  u32x4 kB[8];
#pragma unroll
  for (int kq = 0; kq < 8; ++kq)
    kB[kq] = *(const u32x4*)(kb_b + (size_t)sidx * DD +
                             ((kOff + hi * 8 + kq * 32) ^ mS));
  u32x4 kt0[4], kt1[4], fA0, fA1, fB0, fB1;
  {
    const u16* ktc = kbt + (size_t)(b * NC + 0) * CC * DD;
#pragma unroll
    for (int t = 0; t < 4; ++t) {
      int k = 16 * (4 * wid + t) + lo;
      const u16* rowp = ktc + (size_t)k * 64;
      int m = sx6(k) << 3;
      kt0[t] = *(const u32x4*)(rowp + ((8 * hi) ^ m));
      kt1[t] = *(const u32x4*)(rowp + ((8 * hi + 32) ^ m));
    }
    size_t tbase = ((size_t)(b * NC + 0) * 64 + sidx) * 64 + hi * 8;
    const u16* mA = (kh == 0) ? tbs : p1g;
    const u16* mB = (kh == 0) ? tcs : p2g;
    fA0 = *(const u32x4*)(mA + tbase);
    fA1 = *(const u32x4*)(mA + tbase + 32);
    fB0 = *(const u32x4*)(mB + tbase);
    fB1 = *(const u32x4*)(mB + tbase + 32);
  }
  f32x4 Sa[4];
#pragma unroll
  for (int t = 0; t < 4; ++t) Sa[t] = (f32x4){0.f, 0.f, 0.f, 0.f};
  barrier_all();

  for (int c = 0; c < NC; ++c) {
    // ---- phase UV: [U;V] partials, K from regs; acc -> bf16 per-kh tiles ----
    {
      f32x4 A0 = {0.f,0.f,0.f,0.f}, A1 = {0.f,0.f,0.f,0.f};
#pragma unroll
      for (int kq = 0; kq < 8; ++kq) {
        int col = kOff + hi * 8 + kq * 32;
        bf16x8 sA = ldf(Sb + lo * DD + (col ^ mLo));
        if (kq & 1) A1 = __builtin_amdgcn_mfma_f32_16x16x32_bf16(sA, bcv(kB[kq]), A1, 0, 0, 0);
        else        A0 = __builtin_amdgcn_mfma_f32_16x16x32_bf16(sA, bcv(kB[kq]), A0, 0, 0, 0);
      }
      f32x4 F = A0 + A1;
      if (hi < 2) {
#pragma unroll
        for (int r = 0; r < 4; ++r) {
          int m = 4 * hi + r;   // U row
          Ut2[kh][m * 64 + (sidx ^ (sx6(m) << 3))] = f2bf(F[r]);
        }
      } else {
#pragma unroll
        for (int r = 0; r < 4; ++r) {
          int m = 4 * hi + r - 8;  // V row
          Vt2[kh][m * 64 + (sidx ^ (sx6(m) << 3))] = f2bf(F[r]);
        }
      }
    }
    // prefetch kB for c+1 (regs free after UV)
    if (c + 1 < NC) {
      const u16* src = kb_b + ((size_t)(c + 1) * CC + sidx) * DD;
#pragma unroll
      for (int kq = 0; kq < 8; ++kq)
        kB[kq] = *(const u32x4*)(src + ((kOff + hi * 8 + kq * 32) ^ mS));
    }
    barrier_lgkm();
    // ---- B (kh0: Ws) || C (kh1: y), K=128 over both halves ----
    {
      f32x4 Wa0 = {0.f,0.f,0.f,0.f}, Wa1 = {0.f,0.f,0.f,0.f};
#pragma unroll
      for (int h = 0; h < 2; ++h) {
        bf16x8 vf0 = ldf(Vt2[h] + lo * 64 + ((hi * 8) ^ mLo));
        bf16x8 vf1 = ldf(Vt2[h] + lo * 64 + ((hi * 8 + 32) ^ mLo));
        bf16x8 uf0 = ldf(Ut2[h] + lo * 64 + ((hi * 8) ^ mLo));
        bf16x8 uf1 = ldf(Ut2[h] + lo * 64 + ((hi * 8 + 32) ^ mLo));
        Wa0 = __builtin_amdgcn_mfma_f32_16x16x32_bf16(vf0, bcv(fA0), Wa0, 0, 0, 0);
        Wa1 = __builtin_amdgcn_mfma_f32_16x16x32_bf16(vf1, bcv(fA1), Wa1, 0, 0, 0);
        Wa0 = __builtin_amdgcn_mfma_f32_16x16x32_bf16(uf0, bcv(fB0), Wa0, 0, 0, 0);
        Wa1 = __builtin_amdgcn_mfma_f32_16x16x32_bf16(uf1, bcv(fB1), Wa1, 0, 0, 0);
      }
      f32x4 Wa = Wa0 + Wa1;
      if (kh == 0) {
        if (hi < 2) {
#pragma unroll
          for (int r = 0; r < 4; ++r) {
            int v = 4 * hi + r;
            Ws[v * 64 + (sidx ^ (sx6(v) << 3))] = f2bf(Wa[r]);
          }
        }
      } else {
        if (hi < 2) {
          float4 yo = make_float4(Wa[0], Wa[1], Wa[2], Wa[3]);
          *(float4*)(yb + (size_t)(c * CC + sidx) * DD + v0 + 4 * hi) = yo;
        }
      }
    }
    barrier_lgkm();
    // ---- phase D: S = lam64*S + Ws^T.K ----
    {
      bf16x8 ws0 = ldf(Ws + lo * 64 + ((hi * 8) ^ mLo));
      bf16x8 ws1 = ldf(Ws + lo * 64 + ((hi * 8 + 32) ^ mLo));
#pragma unroll
      for (int t = 0; t < 4; ++t) {
        f32x4 acc = Sa[t] * lam64;
        acc = __builtin_amdgcn_mfma_f32_16x16x32_bf16(ws0, bcv(kt0[t]), acc, 0, 0, 0);
        acc = __builtin_amdgcn_mfma_f32_16x16x32_bf16(ws1, bcv(kt1[t]), acc, 0, 0, 0);
        Sa[t] = acc;
      }
      if (hi < 2) {
#pragma unroll
        for (int t = 0; t < 4; ++t) {
          int kc = 16 * (4 * wid + t) + lo;
#pragma unroll
          for (int r = 0; r < 4; ++r) {
            int v = 4 * hi + r;
            Sb[v * DD + (kc ^ (sx6(v) << 3))] = f2bf(Sa[t][r]);
          }
        }
      }
    }
    // ---- prefetch kt/frames for c+1 ----
    if (c + 1 < NC) {
      const u16* ktc = kbt + (size_t)(b * NC + c + 1) * CC * DD;
#pragma unroll
      for (int t = 0; t < 4; ++t) {
        int k = 16 * (4 * wid + t) + lo;
        const u16* rowp = ktc + (size_t)k * 64;
        int m = sx6(k) << 3;
        kt0[t] = *(const u32x4*)(rowp + ((8 * hi) ^ m));
        kt1[t] = *(const u32x4*)(rowp + ((8 * hi + 32) ^ m));
      }
      size_t tbase = ((size_t)(b * NC + c + 1) * 64 + sidx) * 64 + hi * 8;
      const u16* mA = (kh == 0) ? tbs : p1g;
      const u16* mB = (kh == 0) ? tcs : p2g;
      fA0 = *(const u32x4*)(mA + tbase);
      fA1 = *(const u32x4*)(mA + tbase + 32);
      fB0 = *(const u32x4*)(mB + tbase);
      fB1 = *(const u32x4*)(mB + tbase + 32);
    }
    barrier_lgkm();
  }
}

// ---------------------------------------------------------------------------
// K4: LayerNorm in-place on d_out.
// ---------------------------------------------------------------------------
__global__ __launch_bounds__(256) void k_ln(float* __restrict__ y,
                                            const float* __restrict__ gamma,
                                            const float* __restrict__ lbeta) {
  int row = blockIdx.x * 4 + (threadIdx.x >> 6);
  int lane = threadIdx.x & 63;
  float* yr = y + (size_t)row * DD + lane * 8;
  float4 a = *(const float4*)yr;
  float4 b = *(const float4*)(yr + 4);
  float v[8] = {a.x, a.y, a.z, a.w, b.x, b.y, b.z, b.w};
  float s = 0.f, ss = 0.f;
#pragma unroll
  for (int j = 0; j < 8; ++j) {
    s += v[j];
    ss = fmaf(v[j], v[j], ss);
  }
#pragma unroll
  for (int m = 1; m < 64; m <<= 1) {
    s += __shfl_xor(s, m, 64);
    ss += __shfl_xor(ss, m, 64);
  }
  float mu = s * (1.f / DD);
  float var = ss * (1.f / DD) - mu * mu;
  float inv = rsqrtf(var + EPSF);
  const float* gp = gamma + lane * 8;
  const float* bp = lbeta + lane * 8;
  float4 g0 = *(const float4*)gp;
  float4 g1 = *(const float4*)(gp + 4);
  float4 b0 = *(const float4*)bp;
  float4 b1 = *(const float4*)(bp + 4);
  float g[8] = {g0.x, g0.y, g0.z, g0.w, g1.x, g1.y, g1.z, g1.w};
  float bb[8] = {b0.x, b0.y, b0.z, b0.w, b1.x, b1.y, b1.z, b1.w};
#pragma unroll
  for (int j = 0; j < 8; ++j) v[j] = (v[j] - mu) * inv * g[j] + bb[j];
  *(float4*)yr = make_float4(v[0], v[1], v[2], v[3]);
  *(float4*)(yr + 4) = make_float4(v[4], v[5], v[6], v[7]);
}

// ---------------------------------------------------------------------------
extern "C" void kernel_launch(void* const* d_in, const int* in_sizes, int n_in,
                              void* d_out, int out_size, void* d_ws, size_t ws_size,
                              hipStream_t stream) {
  const float* x     = (const float*)d_in[0];
  const float* W     = (const float*)d_in[1];
  const float* eta   = (const float*)d_in[2];
  const float* ll    = (const float*)d_in[3];
  const float* gamma = (const float*)d_in[4];
  const float* lbeta = (const float*)d_in[5];
  float* out = (float*)d_out;

  // ws (u16): kbs 8MB | kbt 8MB | wbb 0.5MB | tbs/tcs/p1/p2 1MB each (~20.5MB)
  u16* kbs = (u16*)d_ws;
  u16* kbt = kbs + (size_t)BB * LL * DD;
  u16* wbb = kbt + (size_t)BB * LL * DD;
  u16* tbs = wbb + (size_t)DD * DD;
  u16* tcs = tbs + (size_t)BB * NC * 64 * 64;
  u16* p1g = tcs + (size_t)BB * NC * 64 * 64;
  u16* p2g = p1g + (size_t)BB * NC * 64 * 64;

  k_cvtW<<<128, 256, 0, stream>>>(W, wbb);
  k_prep3<<<BB * NC, 256, 0, stream>>>(x, eta, ll, kbs, tbs, tcs, p1g, p2g, kbt);
  k_scanC<<<256, 512, 0, stream>>>(kbs, kbt, wbb, tbs, tcs, p1g, p2g, ll, out);
  k_ln<<<2048, 256, 0, stream>>>(out, gamma, lbeta);
}

// Round 14
// 137.586 us; speedup vs baseline: 4.4455x; 1.0639x over previous
//
#include <hip/hip_runtime.h>
#include <math.h>

#define BB 4
#define LL 2048
#define DD 512
#define CC 64      // chunk length
#define NC 32      // number of chunks
#define VB 8       // v-columns owned per workgroup
#define EPSF 1e-5f

typedef unsigned int u32;
typedef unsigned short u16;
typedef __attribute__((ext_vector_type(4))) u32 u32x4;
typedef __attribute__((ext_vector_type(4))) float f32x4;
typedef __attribute__((ext_vector_type(8))) __bf16 bf16x8;

__device__ __forceinline__ u16 f2bf(float f) {           // native RNE cvt
  return __builtin_bit_cast(u16, (__bf16)f);
}
__device__ __forceinline__ int sx6(int s) { return (s ^ (s >> 3)) & 7; }
__device__ __forceinline__ bf16x8 ldf(const u16* p) {
  return __builtin_bit_cast(bf16x8, *(const u32x4*)p);
}
__device__ __forceinline__ bf16x8 bcv(u32x4 v) { return __builtin_bit_cast(bf16x8, v); }

__device__ __forceinline__ void gld16(u16* lds, const u16* g) {
  __builtin_amdgcn_global_load_lds(
      (const __attribute__((address_space(1))) u32*)g,
      (__attribute__((address_space(3))) u32*)lds, 16, 0, 0);
}
// barrier that drains only LDS (keeps global loads in flight)
__device__ __forceinline__ void barrier_lgkm() {
  asm volatile("s_waitcnt lgkmcnt(0)" ::: "memory");
  __builtin_amdgcn_sched_barrier(0);
  __builtin_amdgcn_s_barrier();
  __builtin_amdgcn_sched_barrier(0);
}
__device__ __forceinline__ void barrier_all() {
  asm volatile("s_waitcnt vmcnt(0) lgkmcnt(0)" ::: "memory");
  __builtin_amdgcn_sched_barrier(0);
  __builtin_amdgcn_s_barrier();
  __builtin_amdgcn_sched_barrier(0);
}

// ---------------------------------------------------------------------------
// K1: fused elementwise pre-pass.
//   blocks [0,2048): x_act = tanh(x) -> kbs (pre-swizzled bf16 rows)
//   blocks [2048,2176): W -> bf16 row-major (wbb)
// ---------------------------------------------------------------------------
__global__ __launch_bounds__(256) void k_pre(const float* __restrict__ x,
                                             const float* __restrict__ W,
                                             u16* __restrict__ kbs,
                                             u16* __restrict__ wbb) {
  int blk = blockIdx.x;
  if (blk < 2048) {
    int row  = blk * 4 + (threadIdx.x >> 6);
    int lane = threadIdx.x & 63;
    const float* xr = x + (size_t)row * DD + lane * 8;
    float4 a = *(const float4*)xr;
    float4 b = *(const float4*)(xr + 4);
    float v[8] = {a.x, a.y, a.z, a.w, b.x, b.y, b.z, b.w};
    u32x4 pk;
#pragma unroll
    for (int j = 0; j < 4; ++j) {
      u16 h0 = f2bf(tanhf(v[2 * j]));
      u16 h1 = f2bf(tanhf(v[2 * j + 1]));
      pk[j] = (u32)h0 | ((u32)h1 << 16);
    }
    int s = row & 63;
    int k0 = (lane * 8) ^ (sx6(s) << 3);
    *(u32x4*)(kbs + (size_t)row * DD + k0) = pk;
  } else {
    int idx = ((blk - 2048) * 256 + threadIdx.x) * 8;
    float4 a = *(const float4*)(W + idx);
    float4 b = *(const float4*)(W + idx + 4);
    float v[8] = {a.x, a.y, a.z, a.w, b.x, b.y, b.z, b.w};
    u32x4 pk;
#pragma unroll
    for (int j = 0; j < 4; ++j)
      pk[j] = (u32)f2bf(v[2 * j]) | ((u32)f2bf(v[2 * j + 1]) << 16);
    *(u32x4*)(wbb + idx) = pk;
  }
}

// ---------------------------------------------------------------------------
// K2: kbs -> kbt transpose (K^T, swizzled).  512 WGs = (b,c) x 4 quarters.
//   Stage 16 rows (de-swizzled) into linear LDS, then each thread packs
//   2 k-rows x 16 s-entries into two u32x4 kbt writes.
// ---------------------------------------------------------------------------
__global__ __launch_bounds__(256) void k_trans(const u16* __restrict__ kbs,
                                               u16* __restrict__ kbt) {
  __shared__ __align__(16) u16 Ls[16 * 520];  // +8 pad per row vs bank aliasing
  int bc = blockIdx.x >> 2;
  int q = blockIdx.x & 3;
  int b = bc >> 5, c = bc & 31;
  int tid = threadIdx.x;
  int s0 = q * 16;
  const u16* kbs_c = kbs + (size_t)(b * LL + c * CC) * DD;
  u16* ktb = kbt + (size_t)bc * CC * DD;
#pragma unroll
  for (int i = 0; i < 4; ++i) {
    int idx = tid + i * 256;
    int r = idx >> 6;
    int k8 = (idx & 63) * 8;
    int s = s0 + r;
    u32x4 v = *(const u32x4*)(kbs_c + (size_t)s * DD + (k8 ^ (sx6(s) << 3)));
    *(u32x4*)&Ls[r * 520 + k8] = v;
  }
  __syncthreads();
#pragma unroll
  for (int kk = 0; kk < 2; ++kk) {
    int k = tid * 2 + kk;
    int mk = sx6(k) << 3;
#pragma unroll
    for (int g2 = 0; g2 < 2; ++g2) {
      int g = q * 2 + g2;
      u32 w4[4];
#pragma unroll
      for (int p = 0; p < 4; ++p) {
        int sL = g2 * 8 + 2 * p;
        u16 e0 = Ls[sL * 520 + k];
        u16 e1 = Ls[(sL + 1) * 520 + k];
        w4[p] = (u32)e0 | ((u32)e1 << 16);
      }
      *(u32x4*)(ktb + (size_t)k * 64 + ((8 * g) ^ mk)) =
          (u32x4){w4[0], w4[1], w4[2], w4[3]};
    }
  }
}

// ---------------------------------------------------------------------------
// K3: slim per-(b,chunk) prep (G/T/P only; Kl staged by DMA from kbs):
//   G = K K^T (MFMA); T = (I+A)^{-1} (fwd subst, 4 lanes/col)
//   tbs[s][r] = lam^{63-s}*beta*T ; tcs = -lam^{63-s}*beta*T*lam^{r+1}
//   p1g = Mt.(beta*T) + I ; p2g = Mt.(-beta*T*diag(lam^{r+1})) + diag(lam^{s+1})
// ---------------------------------------------------------------------------
__global__ __launch_bounds__(256) void k_prep4(const u16* __restrict__ kbs,
                                               const float* __restrict__ eta_p,
                                               const float* __restrict__ ll_p,
                                               u16* __restrict__ tbs,
                                               u16* __restrict__ tcs,
                                               u16* __restrict__ p1g,
                                               u16* __restrict__ p2g) {
  __shared__ __align__(16) u16 Kl[CC * DD];   // 64 KB (pre-swizzled, DMA copy)
  __shared__ float Gl[64 * 64];
  __shared__ float Gs[64 * 64];
  __shared__ float Tl[64 * 65];
  __shared__ __align__(16) u16 MtL[64 * 64];
  __shared__ __align__(16) u16 TbT[64 * 64];
  __shared__ __align__(16) u16 TcT[64 * 64];
  __shared__ float pw[72];
  int bc = blockIdx.x;
  int b = bc >> 5, c = bc & 31;
  int tid = threadIdx.x;
  int wid = tid >> 6, lane = tid & 63;
  int lo = lane & 15, hi = lane >> 4;
  float beta = *eta_p;
  float lam = 1.f / (1.f + expf(-*ll_p));
  if (tid <= 64) pw[tid] = powf(lam, (float)tid);
  for (int i = tid; i < 64 * 65; i += 256) Tl[i] = 0.f;
  const u16* Kg = kbs + (size_t)(b * LL + c * CC) * DD;
#pragma unroll
  for (int i = 0; i < 16; ++i)
    gld16(Kl + (size_t)(i * 256 + tid) * 8, Kg + (size_t)(i * 256 + tid) * 8);
  __syncthreads();
  // ---- G = K K^T ----
  {
    f32x4 acc[4] = {{0.f,0.f,0.f,0.f},{0.f,0.f,0.f,0.f},{0.f,0.f,0.f,0.f},{0.f,0.f,0.f,0.f}};
    int t = 16 * wid + lo;
    int mT = sx6(t) << 3;
#pragma unroll
    for (int kq = 0; kq < 16; ++kq) {
      int col = hi * 8 + kq * 32;
      bf16x8 aF = ldf(Kl + t * DD + (col ^ mT));
#pragma unroll
      for (int sb = 0; sb < 4; ++sb) {
        int s = 16 * sb + lo;
        bf16x8 bF = ldf(Kl + s * DD + (col ^ (sx6(s) << 3)));
        acc[sb] = __builtin_amdgcn_mfma_f32_16x16x32_bf16(aF, bF, acc[sb], 0, 0, 0);
      }
    }
#pragma unroll
    for (int sb = 0; sb < 4; ++sb)
#pragma unroll
      for (int r = 0; r < 4; ++r)
        Gl[(16 * wid + 4 * hi + r) * 64 + 16 * sb + lo] = acc[sb][r];
  }
  __syncthreads();
#pragma unroll
  for (int i = 0; i < 16; ++i) {
    int idx = tid + i * 256;
    int tq = idx >> 6, sq = idx & 63;
    Gs[idx] = (sq < tq) ? beta * pw[tq - sq] * Gl[idx] : 0.f;
  }
  __syncthreads();
  // ---- forward substitution ----
  {
    int q = hi;
    int j = 16 * wid + lo;
    for (int t = 0; t < 64; ++t) {
      float ps = 0.f;
#pragma unroll
      for (int i = 0; i < 16; ++i) {
        int s = 16 * q + i;
        ps = fmaf(Gs[t * 64 + s], Tl[s * 65 + j], ps);
      }
      ps += __shfl_xor(ps, 16, 64);
      ps += __shfl_xor(ps, 32, 64);
      if (q == 0) Tl[t * 65 + j] = ((t == j) ? 1.f : 0.f) - ps;
    }
  }
  __syncthreads();
  // ---- tbs/tcs + LDS tiles for P GEMMs ----
  u16* tbso = tbs + (size_t)bc * 4096;
  u16* tcso = tcs + (size_t)bc * 4096;
#pragma unroll
  for (int i = 0; i < 16; ++i) {
    int idx = tid + i * 256;
    int s = idx >> 6, r = idx & 63;
    float tv = Tl[s * 65 + r];
    float sc = pw[63 - s] * beta;
    tbso[idx] = f2bf(sc * tv);
    tcso[idx] = f2bf(-sc * pw[r + 1] * tv);
    int swz = r ^ (sx6(s) << 3);
    float mtv = (r < s) ? pw[s - r] * Gl[s * 64 + r]
                        : ((r == s) ? Gl[s * 64 + r] : 0.f);
    MtL[s * 64 + swz] = f2bf(mtv);
    float tvT = Tl[r * 65 + s];
    TbT[s * 64 + swz] = f2bf(beta * tvT);
    TcT[s * 64 + swz] = f2bf(-beta * pw[s + 1] * tvT);
  }
  __syncthreads();
  // ---- P1 = Mt.Tb + I, P2 = Mt.Tc + diag(lam^{s+1}) ----
  {
    f32x4 p1a[4], p2a[4];
#pragma unroll
    for (int rt = 0; rt < 4; ++rt) {
      p1a[rt] = (f32x4){0.f, 0.f, 0.f, 0.f};
      p2a[rt] = (f32x4){0.f, 0.f, 0.f, 0.f};
    }
    int srow = 16 * wid + lo;
    int aswz = sx6(srow) << 3;
#pragma unroll
    for (int km = 0; km < 2; ++km) {
      int mo = hi * 8 + km * 32;
      bf16x8 aF = ldf(MtL + srow * 64 + (mo ^ aswz));
#pragma unroll
      for (int rt = 0; rt < 4; ++rt) {
        int rrow = 16 * rt + lo;
        int bswz = sx6(rrow) << 3;
        p1a[rt] = __builtin_amdgcn_mfma_f32_16x16x32_bf16(
            aF, ldf(TbT + rrow * 64 + (mo ^ bswz)), p1a[rt], 0, 0, 0);
        p2a[rt] = __builtin_amdgcn_mfma_f32_16x16x32_bf16(
            aF, ldf(TcT + rrow * 64 + (mo ^ bswz)), p2a[rt], 0, 0, 0);
      }
    }
    u16* p1o = p1g + (size_t)bc * 4096;
    u16* p2o = p2g + (size_t)bc * 4096;
#pragma unroll
    for (int rt = 0; rt < 4; ++rt)
#pragma unroll
      for (int rg = 0; rg < 4; ++rg) {
        int s = 16 * wid + 4 * hi + rg;
        int r = 16 * rt + lo;
        float d1 = (s == r) ? 1.f : 0.f;
        float d2 = (s == r) ? pw[s + 1] : 0.f;
        p1o[s * 64 + r] = f2bf(p1a[rt][rg] + d1);
        p2o[s * 64 + r] = f2bf(p2a[rt][rg] + d2);
      }
  }
}

// ---------------------------------------------------------------------------
// K4: MFMA chunked scan vC (+T5 setprio). VB=8, 256 WGs, 8 waves, 2 w/SIMD.
//   UV(8 mfma) -> bar -> B(kh0)||C->y(kh1) K=128 -> bar -> D(8) -> bar
// ---------------------------------------------------------------------------
__global__ __launch_bounds__(512, 2) void k_scanC(const u16* __restrict__ kbs,
                                                  const u16* __restrict__ kbt,
                                                  const u16* __restrict__ wbb,
                                                  const u16* __restrict__ tbs,
                                                  const u16* __restrict__ tcs,
                                                  const u16* __restrict__ p1g,
                                                  const u16* __restrict__ p2g,
                                                  const float* __restrict__ ll_p,
                                                  float* __restrict__ y) {
  __shared__ __align__(16) u16 Sb[16 * DD];     // rows0-7 S^T, rows8-15 W
  __shared__ __align__(16) u16 Ut2[2][16 * 64]; // per-kh U^T tiles (rows 0-7)
  __shared__ __align__(16) u16 Vt2[2][16 * 64]; // per-kh V^T tiles (rows 0-7)
  __shared__ __align__(16) u16 Ws[16 * 64];

  int b = blockIdx.x >> 6;
  int vb = blockIdx.x & 63;
  int v0 = vb * VB;
  int tid = threadIdx.x;
  int wid = tid >> 6, lane = tid & 63;
  int wq = wid & 3, kh = wid >> 2;
  int lo = lane & 15, hi = lane >> 4;
  int sidx = 16 * wq + lo;
  int mS = sx6(sidx) << 3;
  int mLo = sx6(lo) << 3;
  int kOff = kh * 256;

  float lam = 1.f / (1.f + expf(-*ll_p));
  float lam64 = powf(lam, 64.f);

  {
    u32x4 z = {0u, 0u, 0u, 0u};
    ((u32x4*)Sb)[tid] = z;
    if (tid < 256) {
      ((u32x4*)Ut2)[tid] = z;
      ((u32x4*)Vt2)[tid] = z;
    }
    if (tid < 128) ((u32x4*)Ws)[tid] = z;
    if (wid < 8) {
      u32x4 wrow = *(const u32x4*)(wbb + (size_t)(v0 + wid) * DD + lane * 8);
      *(u32x4*)(Sb + (size_t)(8 + wid) * DD + ((lane * 8) ^ (sx6(8 + wid) << 3))) = wrow;
    }
  }
  const u16* kb_b = kbs + (size_t)b * LL * DD;
  float* yb = y + (size_t)b * LL * DD;

  u32x4 kB[8];
#pragma unroll
  for (int kq = 0; kq < 8; ++kq)
    kB[kq] = *(const u32x4*)(kb_b + (size_t)sidx * DD +
                             ((kOff + hi * 8 + kq * 32) ^ mS));
  u32x4 kt0[4], kt1[4], fA0, fA1, fB0, fB1;
  {
    const u16* ktc = kbt + (size_t)(b * NC + 0) * CC * DD;
#pragma unroll
    for (int t = 0; t < 4; ++t) {
      int k = 16 * (4 * wid + t) + lo;
      const u16* rowp = ktc + (size_t)k * 64;
      int m = sx6(k) << 3;
      kt0[t] = *(const u32x4*)(rowp + ((8 * hi) ^ m));
      kt1[t] = *(const u32x4*)(rowp + ((8 * hi + 32) ^ m));
    }
    size_t tbase = ((size_t)(b * NC + 0) * 64 + sidx) * 64 + hi * 8;
    const u16* mA = (kh == 0) ? tbs : p1g;
    const u16* mB = (kh == 0) ? tcs : p2g;
    fA0 = *(const u32x4*)(mA + tbase);
    fA1 = *(const u32x4*)(mA + tbase + 32);
    fB0 = *(const u32x4*)(mB + tbase);
    fB1 = *(const u32x4*)(mB + tbase + 32);
  }
  f32x4 Sa[4];
#pragma unroll
  for (int t = 0; t < 4; ++t) Sa[t] = (f32x4){0.f, 0.f, 0.f, 0.f};
  barrier_all();

  for (int c = 0; c < NC; ++c) {
    // ---- phase UV ----
    {
      f32x4 A0 = {0.f,0.f,0.f,0.f}, A1 = {0.f,0.f,0.f,0.f};
      __builtin_amdgcn_s_setprio(1);
#pragma unroll
      for (int kq = 0; kq < 8; ++kq) {
        int col = kOff + hi * 8 + kq * 32;
        bf16x8 sA = ldf(Sb + lo * DD + (col ^ mLo));
        if (kq & 1) A1 = __builtin_amdgcn_mfma_f32_16x16x32_bf16(sA, bcv(kB[kq]), A1, 0, 0, 0);
        else        A0 = __builtin_amdgcn_mfma_f32_16x16x32_bf16(sA, bcv(kB[kq]), A0, 0, 0, 0);
      }
      __builtin_amdgcn_s_setprio(0);
      f32x4 F = A0 + A1;
      if (hi < 2) {
#pragma unroll
        for (int r = 0; r < 4; ++r) {
          int m = 4 * hi + r;
          Ut2[kh][m * 64 + (sidx ^ (sx6(m) << 3))] = f2bf(F[r]);
        }
      } else {
#pragma unroll
        for (int r = 0; r < 4; ++r) {
          int m = 4 * hi + r - 8;
          Vt2[kh][m * 64 + (sidx ^ (sx6(m) << 3))] = f2bf(F[r]);
        }
      }
    }
    if (c + 1 < NC) {
      const u16* src = kb_b + ((size_t)(c + 1) * CC + sidx) * DD;
#pragma unroll
      for (int kq = 0; kq < 8; ++kq)
        kB[kq] = *(const u32x4*)(src + ((kOff + hi * 8 + kq * 32) ^ mS));
    }
    barrier_lgkm();
    // ---- B (kh0: Ws) || C (kh1: y), K=128 ----
    {
      f32x4 Wa0 = {0.f,0.f,0.f,0.f}, Wa1 = {0.f,0.f,0.f,0.f};
      __builtin_amdgcn_s_setprio(1);
#pragma unroll
      for (int h = 0; h < 2; ++h) {
        bf16x8 vf0 = ldf(Vt2[h] + lo * 64 + ((hi * 8) ^ mLo));
        bf16x8 vf1 = ldf(Vt2[h] + lo * 64 + ((hi * 8 + 32) ^ mLo));
        bf16x8 uf0 = ldf(Ut2[h] + lo * 64 + ((hi * 8) ^ mLo));
        bf16x8 uf1 = ldf(Ut2[h] + lo * 64 + ((hi * 8 + 32) ^ mLo));
        Wa0 = __builtin_amdgcn_mfma_f32_16x16x32_bf16(vf0, bcv(fA0), Wa0, 0, 0, 0);
        Wa1 = __builtin_amdgcn_mfma_f32_16x16x32_bf16(vf1, bcv(fA1), Wa1, 0, 0, 0);
        Wa0 = __builtin_amdgcn_mfma_f32_16x16x32_bf16(uf0, bcv(fB0), Wa0, 0, 0, 0);
        Wa1 = __builtin_amdgcn_mfma_f32_16x16x32_bf16(uf1, bcv(fB1), Wa1, 0, 0, 0);
      }
      __builtin_amdgcn_s_setprio(0);
      f32x4 Wa = Wa0 + Wa1;
      if (kh == 0) {
        if (hi < 2) {
#pragma unroll
          for (int r = 0; r < 4; ++r) {
            int v = 4 * hi + r;
            Ws[v * 64 + (sidx ^ (sx6(v) << 3))] = f2bf(Wa[r]);
          }
        }
      } else {
        if (hi < 2) {
          float4 yo = make_float4(Wa[0], Wa[1], Wa[2], Wa[3]);
          *(float4*)(yb + (size_t)(c * CC + sidx) * DD + v0 + 4 * hi) = yo;
        }
      }
    }
    barrier_lgkm();
    // ---- phase D: S = lam64*S + Ws^T.K ----
    {
      bf16x8 ws0 = ldf(Ws + lo * 64 + ((hi * 8) ^ mLo));
      bf16x8 ws1 = ldf(Ws + lo * 64 + ((hi * 8 + 32) ^ mLo));
      __builtin_amdgcn_s_setprio(1);
#pragma unroll
      for (int t = 0; t < 4; ++t) {
        f32x4 acc = Sa[t] * lam64;
        acc = __builtin_amdgcn_mfma_f32_16x16x32_bf16(ws0, bcv(kt0[t]), acc, 0, 0, 0);
        acc = __builtin_amdgcn_mfma_f32_16x16x32_bf16(ws1, bcv(kt1[t]), acc, 0, 0, 0);
        Sa[t] = acc;
      }
      __builtin_amdgcn_s_setprio(0);
      if (hi < 2) {
#pragma unroll
        for (int t = 0; t < 4; ++t) {
          int kc = 16 * (4 * wid + t) + lo;
#pragma unroll
          for (int r = 0; r < 4; ++r) {
            int v = 4 * hi + r;
            Sb[v * DD + (kc ^ (sx6(v) << 3))] = f2bf(Sa[t][r]);
          }
        }
      }
    }
    if (c + 1 < NC) {
      const u16* ktc = kbt + (size_t)(b * NC + c + 1) * CC * DD;
#pragma unroll
      for (int t = 0; t < 4; ++t) {
        int k = 16 * (4 * wid + t) + lo;
        const u16* rowp = ktc + (size_t)k * 64;
        int m = sx6(k) << 3;
        kt0[t] = *(const u32x4*)(rowp + ((8 * hi) ^ m));
        kt1[t] = *(const u32x4*)(rowp + ((8 * hi + 32) ^ m));
      }
      size_t tbase = ((size_t)(b * NC + c + 1) * 64 + sidx) * 64 + hi * 8;
      const u16* mA = (kh == 0) ? tbs : p1g;
      const u16* mB = (kh == 0) ? tcs : p2g;
      fA0 = *(const u32x4*)(mA + tbase);
      fA1 = *(const u32x4*)(mA + tbase + 32);
      fB0 = *(const u32x4*)(mB + tbase);
      fB1 = *(const u32x4*)(mB + tbase + 32);
    }
    barrier_lgkm();
  }
}

// ---------------------------------------------------------------------------
// K5: LayerNorm in-place on d_out.
// ---------------------------------------------------------------------------
__global__ __launch_bounds__(256) void k_ln(float* __restrict__ y,
                                            const float* __restrict__ gamma,
                                            const float* __restrict__ lbeta) {
  int row = blockIdx.x * 4 + (threadIdx.x >> 6);
  int lane = threadIdx.x & 63;
  float* yr = y + (size_t)row * DD + lane * 8;
  float4 a = *(const float4*)yr;
  float4 b = *(const float4*)(yr + 4);
  float v[8] = {a.x, a.y, a.z, a.w, b.x, b.y, b.z, b.w};
  float s = 0.f, ss = 0.f;
#pragma unroll
  for (int j = 0; j < 8; ++j) {
    s += v[j];
    ss = fmaf(v[j], v[j], ss);
  }
#pragma unroll
  for (int m = 1; m < 64; m <<= 1) {
    s += __shfl_xor(s, m, 64);
    ss += __shfl_xor(ss, m, 64);
  }
  float mu = s * (1.f / DD);
  float var = ss * (1.f / DD) - mu * mu;
  float inv = rsqrtf(var + EPSF);
  const float* gp = gamma + lane * 8;
  const float* bp = lbeta + lane * 8;
  float4 g0 = *(const float4*)gp;
  float4 g1 = *(const float4*)(gp + 4);
  float4 b0 = *(const float4*)bp;
  float4 b1 = *(const float4*)(bp + 4);
  float g[8] = {g0.x, g0.y, g0.z, g0.w, g1.x, g1.y, g1.z, g1.w};
  float bb[8] = {b0.x, b0.y, b0.z, b0.w, b1.x, b1.y, b1.z, b1.w};
#pragma unroll
  for (int j = 0; j < 8; ++j) v[j] = (v[j] - mu) * inv * g[j] + bb[j];
  *(float4*)yr = make_float4(v[0], v[1], v[2], v[3]);
  *(float4*)(yr + 4) = make_float4(v[4], v[5], v[6], v[7]);
}

// ---------------------------------------------------------------------------
extern "C" void kernel_launch(void* const* d_in, const int* in_sizes, int n_in,
                              void* d_out, int out_size, void* d_ws, size_t ws_size,
                              hipStream_t stream) {
  const float* x     = (const float*)d_in[0];
  const float* W     = (const float*)d_in[1];
  const float* eta   = (const float*)d_in[2];
  const float* ll    = (const float*)d_in[3];
  const float* gamma = (const float*)d_in[4];
  const float* lbeta = (const float*)d_in[5];
  float* out = (float*)d_out;

  // ws (u16): kbs 8MB | kbt 8MB | wbb 0.5MB | tbs/tcs/p1/p2 1MB each (~20.5MB)
  u16* kbs = (u16*)d_ws;
  u16* kbt = kbs + (size_t)BB * LL * DD;
  u16* wbb = kbt + (size_t)BB * LL * DD;
  u16* tbs = wbb + (size_t)DD * DD;
  u16* tcs = tbs + (size_t)BB * NC * 64 * 64;
  u16* p1g = tcs + (size_t)BB * NC * 64 * 64;
  u16* p2g = p1g + (size_t)BB * NC * 64 * 64;

  k_pre<<<2176, 256, 0, stream>>>(x, W, kbs, wbb);
  k_trans<<<512, 256, 0, stream>>>(kbs, kbt);
  k_prep4<<<BB * NC, 256, 0, stream>>>(kbs, eta, ll, tbs, tcs, p1g, p2g);
  k_scanC<<<256, 512, 0, stream>>>(kbs, kbt, wbb, tbs, tcs, p1g, p2g, ll, out);
  k_ln<<<2048, 256, 0, stream>>>(out, gamma, lbeta);
}

// Round 15
// 131.147 us; speedup vs baseline: 4.6638x; 1.0491x over previous
//
#include <hip/hip_runtime.h>
#include <math.h>

#define BB 4
#define LL 2048
#define DD 512
#define CC 64      // chunk length
#define NC 32      // number of chunks
#define VB 8       // v-columns owned per workgroup
#define EPSF 1e-5f

typedef unsigned int u32;
typedef unsigned short u16;
typedef __attribute__((ext_vector_type(4))) u32 u32x4;
typedef __attribute__((ext_vector_type(4))) float f32x4;
typedef __attribute__((ext_vector_type(8))) __bf16 bf16x8;

__device__ __forceinline__ u16 f2bf(float f) {           // native RNE cvt
  return __builtin_bit_cast(u16, (__bf16)f);
}
__device__ __forceinline__ int sx6(int s) { return (s ^ (s >> 3)) & 7; }
__device__ __forceinline__ bf16x8 ldf(const u16* p) {
  return __builtin_bit_cast(bf16x8, *(const u32x4*)p);
}
__device__ __forceinline__ bf16x8 bcv(u32x4 v) { return __builtin_bit_cast(bf16x8, v); }

__device__ __forceinline__ void gld16(u16* lds, const u16* g) {
  __builtin_amdgcn_global_load_lds(
      (const __attribute__((address_space(1))) u32*)g,
      (__attribute__((address_space(3))) u32*)lds, 16, 0, 0);
}
// barrier that drains only LDS (keeps global loads in flight)
__device__ __forceinline__ void barrier_lgkm() {
  asm volatile("s_waitcnt lgkmcnt(0)" ::: "memory");
  __builtin_amdgcn_sched_barrier(0);
  __builtin_amdgcn_s_barrier();
  __builtin_amdgcn_sched_barrier(0);
}
__device__ __forceinline__ void barrier_all() {
  asm volatile("s_waitcnt vmcnt(0) lgkmcnt(0)" ::: "memory");
  __builtin_amdgcn_sched_barrier(0);
  __builtin_amdgcn_s_barrier();
  __builtin_amdgcn_sched_barrier(0);
}

// ---------------------------------------------------------------------------
// K1: fused pre-pass.
//   blocks [0,512): quarter-chunk: tanh(x)->kbs (swizzled) AND kbt transpose
//   blocks [512,640): W -> bf16 row-major (wbb)
// ---------------------------------------------------------------------------
__global__ __launch_bounds__(256) void k_pre2(const float* __restrict__ x,
                                              const float* __restrict__ W,
                                              u16* __restrict__ kbs,
                                              u16* __restrict__ wbb,
                                              u16* __restrict__ kbt) {
  __shared__ __align__(16) u16 Ls[16 * 520];
  int blk = blockIdx.x;
  int tid = threadIdx.x;
  if (blk < 512) {
    int bc = blk >> 2;
    int q = blk & 3;
    int b = bc >> 5, c = bc & 31;
    int s0 = q * 16;
    const float* xg = x + (size_t)(b * LL + c * CC + s0) * DD;
    u16* kbs_c = kbs + (size_t)(b * LL + c * CC + s0) * DD;
#pragma unroll
    for (int i = 0; i < 4; ++i) {
      int idx = tid + i * 256;
      int r = idx >> 6, k8 = (idx & 63) * 8;
      const float* xp = xg + (size_t)r * DD + k8;
      float4 a = *(const float4*)xp;
      float4 b4 = *(const float4*)(xp + 4);
      float v[8] = {a.x, a.y, a.z, a.w, b4.x, b4.y, b4.z, b4.w};
      u32x4 pk;
#pragma unroll
      for (int j = 0; j < 4; ++j)
        pk[j] = (u32)f2bf(tanhf(v[2 * j])) | ((u32)f2bf(tanhf(v[2 * j + 1])) << 16);
      int s = s0 + r;
      *(u32x4*)(kbs_c + (size_t)r * DD + (k8 ^ (sx6(s) << 3))) = pk;
      *(u32x4*)&Ls[r * 520 + k8] = pk;
    }
    __syncthreads();
    u16* ktb = kbt + (size_t)bc * CC * DD;
#pragma unroll
    for (int kk = 0; kk < 2; ++kk) {
      int k = tid * 2 + kk;
      int mk = sx6(k) << 3;
#pragma unroll
      for (int g2 = 0; g2 < 2; ++g2) {
        int g = q * 2 + g2;
        u32 w4[4];
#pragma unroll
        for (int p = 0; p < 4; ++p) {
          int sL = g2 * 8 + 2 * p;
          u16 e0 = Ls[sL * 520 + k];
          u16 e1 = Ls[(sL + 1) * 520 + k];
          w4[p] = (u32)e0 | ((u32)e1 << 16);
        }
        *(u32x4*)(ktb + (size_t)k * 64 + ((8 * g) ^ mk)) =
            (u32x4){w4[0], w4[1], w4[2], w4[3]};
      }
    }
  } else {
    int idx = ((blk - 512) * 256 + tid) * 8;
    float4 a = *(const float4*)(W + idx);
    float4 b = *(const float4*)(W + idx + 4);
    float v[8] = {a.x, a.y, a.z, a.w, b.x, b.y, b.z, b.w};
    u32x4 pk;
#pragma unroll
    for (int j = 0; j < 4; ++j)
      pk[j] = (u32)f2bf(v[2 * j]) | ((u32)f2bf(v[2 * j + 1]) << 16);
    *(u32x4*)(wbb + idx) = pk;
  }
}

// ---------------------------------------------------------------------------
// K2: slim prep, 512 threads (8 waves).
//   G = K K^T split over k-halves (partials in Gl/Gs, elementwise reduce);
//   Gs-scaling folded into the reduce pass. T fwd-subst on waves 0-3.
//   P1 (kh2=0 waves) / P2 (kh2=1 waves) GEMMs in parallel.
// ---------------------------------------------------------------------------
__global__ __launch_bounds__(512) void k_prep5(const u16* __restrict__ kbs,
                                               const float* __restrict__ eta_p,
                                               const float* __restrict__ ll_p,
                                               u16* __restrict__ tbs,
                                               u16* __restrict__ tcs,
                                               u16* __restrict__ p1g,
                                               u16* __restrict__ p2g) {
  __shared__ __align__(16) u16 Kl[CC * DD];   // 64 KB
  __shared__ float Gl[64 * 64];               // kh2=0 partial, then G
  __shared__ float Gs[64 * 64];               // kh2=1 partial, then scaled
  __shared__ float Tl[64 * 65];
  __shared__ __align__(16) u16 MtL[64 * 64];
  __shared__ __align__(16) u16 TbT[64 * 64];
  __shared__ __align__(16) u16 TcT[64 * 64];
  __shared__ float pw[72];
  int bc = blockIdx.x;
  int b = bc >> 5, c = bc & 31;
  int tid = threadIdx.x;
  int wid = tid >> 6, lane = tid & 63;
  int wq2 = wid & 3, kh2 = wid >> 2;
  int lo = lane & 15, hi = lane >> 4;
  float beta = *eta_p;
  float lam = 1.f / (1.f + expf(-*ll_p));
  if (tid <= 64) pw[tid] = powf(lam, (float)tid);
  for (int i = tid; i < 64 * 65; i += 512) Tl[i] = 0.f;
  const u16* Kg = kbs + (size_t)(b * LL + c * CC) * DD;
#pragma unroll
  for (int i = 0; i < 8; ++i)
    gld16(Kl + (size_t)(i * 512 + tid) * 8, Kg + (size_t)(i * 512 + tid) * 8);
  __syncthreads();
  // ---- G partials: wave (wq2,kh2): t-block 16*wq2, k-half kh2 ----
  {
    f32x4 acc[4] = {{0.f,0.f,0.f,0.f},{0.f,0.f,0.f,0.f},{0.f,0.f,0.f,0.f},{0.f,0.f,0.f,0.f}};
    int t = 16 * wq2 + lo;
    int mT = sx6(t) << 3;
#pragma unroll
    for (int kq = 0; kq < 8; ++kq) {
      int col = kh2 * 256 + hi * 8 + kq * 32;
      bf16x8 aF = ldf(Kl + t * DD + (col ^ mT));
#pragma unroll
      for (int sb = 0; sb < 4; ++sb) {
        int s = 16 * sb + lo;
        bf16x8 bF = ldf(Kl + s * DD + (col ^ (sx6(s) << 3)));
        acc[sb] = __builtin_amdgcn_mfma_f32_16x16x32_bf16(aF, bF, acc[sb], 0, 0, 0);
      }
    }
    float* Gp = kh2 ? Gs : Gl;
#pragma unroll
    for (int sb = 0; sb < 4; ++sb)
#pragma unroll
      for (int r = 0; r < 4; ++r)
        Gp[(16 * wq2 + 4 * hi + r) * 64 + 16 * sb + lo] = acc[sb][r];
  }
  __syncthreads();
  // ---- reduce halves; Gl = G, Gs = scaled strictly-lower ----
#pragma unroll
  for (int i = 0; i < 8; ++i) {
    int idx = tid + i * 512;
    int tq = idx >> 6, sq = idx & 63;
    float g = Gl[idx] + Gs[idx];
    Gl[idx] = g;
    Gs[idx] = (sq < tq) ? beta * pw[tq - sq] * g : 0.f;
  }
  __syncthreads();
  // ---- forward substitution (waves 0-3) ----
  if (tid < 256) {
    int q = hi;
    int j = 16 * wid + lo;
    for (int t = 0; t < 64; ++t) {
      float ps = 0.f;
#pragma unroll
      for (int i = 0; i < 16; ++i) {
        int s = 16 * q + i;
        ps = fmaf(Gs[t * 64 + s], Tl[s * 65 + j], ps);
      }
      ps += __shfl_xor(ps, 16, 64);
      ps += __shfl_xor(ps, 32, 64);
      if (q == 0) Tl[t * 65 + j] = ((t == j) ? 1.f : 0.f) - ps;
    }
  }
  __syncthreads();
  // ---- tbs/tcs + LDS tiles ----
  u16* tbso = tbs + (size_t)bc * 4096;
  u16* tcso = tcs + (size_t)bc * 4096;
#pragma unroll
  for (int i = 0; i < 8; ++i) {
    int idx = tid + i * 512;
    int s = idx >> 6, r = idx & 63;
    float tv = Tl[s * 65 + r];
    float sc = pw[63 - s] * beta;
    tbso[idx] = f2bf(sc * tv);
    tcso[idx] = f2bf(-sc * pw[r + 1] * tv);
    int swz = r ^ (sx6(s) << 3);
    float mtv = (r < s) ? pw[s - r] * Gl[s * 64 + r]
                        : ((r == s) ? Gl[s * 64 + r] : 0.f);
    MtL[s * 64 + swz] = f2bf(mtv);
    float tvT = Tl[r * 65 + s];
    TbT[s * 64 + swz] = f2bf(beta * tvT);
    TcT[s * 64 + swz] = f2bf(-beta * pw[s + 1] * tvT);
  }
  __syncthreads();
  // ---- P1 (kh2=0) / P2 (kh2=1): 8 MFMAs per wave ----
  {
    f32x4 pa[4];
#pragma unroll
    for (int rt = 0; rt < 4; ++rt) pa[rt] = (f32x4){0.f, 0.f, 0.f, 0.f};
    int srow = 16 * wq2 + lo;
    int aswz = sx6(srow) << 3;
    const u16* Bt = kh2 ? TcT : TbT;
#pragma unroll
    for (int km = 0; km < 2; ++km) {
      int mo = hi * 8 + km * 32;
      bf16x8 aF = ldf(MtL + srow * 64 + (mo ^ aswz));
#pragma unroll
      for (int rt = 0; rt < 4; ++rt) {
        int rrow = 16 * rt + lo;
        int bswz = sx6(rrow) << 3;
        pa[rt] = __builtin_amdgcn_mfma_f32_16x16x32_bf16(
            aF, ldf(Bt + rrow * 64 + (mo ^ bswz)), pa[rt], 0, 0, 0);
      }
    }
    u16* po = (kh2 ? p2g : p1g) + (size_t)bc * 4096;
#pragma unroll
    for (int rt = 0; rt < 4; ++rt)
#pragma unroll
      for (int rg = 0; rg < 4; ++rg) {
        int s = 16 * wq2 + 4 * hi + rg;
        int r = 16 * rt + lo;
        float d = kh2 ? ((s == r) ? pw[s + 1] : 0.f)
                      : ((s == r) ? 1.f : 0.f);
        po[s * 64 + r] = f2bf(pa[rt][rg] + d);
      }
  }
}

// ---------------------------------------------------------------------------
// K3: MFMA chunked scan vC (R13 body, no setprio). VB=8, 256 WGs, 8 waves.
//   UV(8 mfma) -> bar -> B(kh0)||C->y(kh1) K=128 -> bar -> D(8) -> bar
// ---------------------------------------------------------------------------
__global__ __launch_bounds__(512, 2) void k_scanC(const u16* __restrict__ kbs,
                                                  const u16* __restrict__ kbt,
                                                  const u16* __restrict__ wbb,
                                                  const u16* __restrict__ tbs,
                                                  const u16* __restrict__ tcs,
                                                  const u16* __restrict__ p1g,
                                                  const u16* __restrict__ p2g,
                                                  const float* __restrict__ ll_p,
                                                  float* __restrict__ y) {
  __shared__ __align__(16) u16 Sb[16 * DD];     // rows0-7 S^T, rows8-15 W
  __shared__ __align__(16) u16 Ut2[2][16 * 64]; // per-kh U^T tiles (rows 0-7)
  __shared__ __align__(16) u16 Vt2[2][16 * 64]; // per-kh V^T tiles (rows 0-7)
  __shared__ __align__(16) u16 Ws[16 * 64];

  int b = blockIdx.x >> 6;
  int vb = blockIdx.x & 63;
  int v0 = vb * VB;
  int tid = threadIdx.x;
  int wid = tid >> 6, lane = tid & 63;
  int wq = wid & 3, kh = wid >> 2;
  int lo = lane & 15, hi = lane >> 4;
  int sidx = 16 * wq + lo;
  int mS = sx6(sidx) << 3;
  int mLo = sx6(lo) << 3;
  int kOff = kh * 256;

  float lam = 1.f / (1.f + expf(-*ll_p));
  float lam64 = powf(lam, 64.f);

  {
    u32x4 z = {0u, 0u, 0u, 0u};
    ((u32x4*)Sb)[tid] = z;
    if (tid < 256) {
      ((u32x4*)Ut2)[tid] = z;
      ((u32x4*)Vt2)[tid] = z;
    }
    if (tid < 128) ((u32x4*)Ws)[tid] = z;
    if (wid < 8) {
      u32x4 wrow = *(const u32x4*)(wbb + (size_t)(v0 + wid) * DD + lane * 8);
      *(u32x4*)(Sb + (size_t)(8 + wid) * DD + ((lane * 8) ^ (sx6(8 + wid) << 3))) = wrow;
    }
  }
  const u16* kb_b = kbs + (size_t)b * LL * DD;
  float* yb = y + (size_t)b * LL * DD;

  u32x4 kB[8];
#pragma unroll
  for (int kq = 0; kq < 8; ++kq)
    kB[kq] = *(const u32x4*)(kb_b + (size_t)sidx * DD +
                             ((kOff + hi * 8 + kq * 32) ^ mS));
  u32x4 kt0[4], kt1[4], fA0, fA1, fB0, fB1;
  {
    const u16* ktc = kbt + (size_t)(b * NC + 0) * CC * DD;
#pragma unroll
    for (int t = 0; t < 4; ++t) {
      int k = 16 * (4 * wid + t) + lo;
      const u16* rowp = ktc + (size_t)k * 64;
      int m = sx6(k) << 3;
      kt0[t] = *(const u32x4*)(rowp + ((8 * hi) ^ m));
      kt1[t] = *(const u32x4*)(rowp + ((8 * hi + 32) ^ m));
    }
    size_t tbase = ((size_t)(b * NC + 0) * 64 + sidx) * 64 + hi * 8;
    const u16* mA = (kh == 0) ? tbs : p1g;
    const u16* mB = (kh == 0) ? tcs : p2g;
    fA0 = *(const u32x4*)(mA + tbase);
    fA1 = *(const u32x4*)(mA + tbase + 32);
    fB0 = *(const u32x4*)(mB + tbase);
    fB1 = *(const u32x4*)(mB + tbase + 32);
  }
  f32x4 Sa[4];
#pragma unroll
  for (int t = 0; t < 4; ++t) Sa[t] = (f32x4){0.f, 0.f, 0.f, 0.f};
  barrier_all();

  for (int c = 0; c < NC; ++c) {
    // ---- phase UV ----
    {
      f32x4 A0 = {0.f,0.f,0.f,0.f}, A1 = {0.f,0.f,0.f,0.f};
#pragma unroll
      for (int kq = 0; kq < 8; ++kq) {
        int col = kOff + hi * 8 + kq * 32;
        bf16x8 sA = ldf(Sb + lo * DD + (col ^ mLo));
        if (kq & 1) A1 = __builtin_amdgcn_mfma_f32_16x16x32_bf16(sA, bcv(kB[kq]), A1, 0, 0, 0);
        else        A0 = __builtin_amdgcn_mfma_f32_16x16x32_bf16(sA, bcv(kB[kq]), A0, 0, 0, 0);
      }
      f32x4 F = A0 + A1;
      if (hi < 2) {
#pragma unroll
        for (int r = 0; r < 4; ++r) {
          int m = 4 * hi + r;
          Ut2[kh][m * 64 + (sidx ^ (sx6(m) << 3))] = f2bf(F[r]);
        }
      } else {
#pragma unroll
        for (int r = 0; r < 4; ++r) {
          int m = 4 * hi + r - 8;
          Vt2[kh][m * 64 + (sidx ^ (sx6(m) << 3))] = f2bf(F[r]);
        }
      }
    }
    if (c + 1 < NC) {
      const u16* src = kb_b + ((size_t)(c + 1) * CC + sidx) * DD;
#pragma unroll
      for (int kq = 0; kq < 8; ++kq)
        kB[kq] = *(const u32x4*)(src + ((kOff + hi * 8 + kq * 32) ^ mS));
    }
    barrier_lgkm();
    // ---- B (kh0: Ws) || C (kh1: y), K=128 ----
    {
      f32x4 Wa0 = {0.f,0.f,0.f,0.f}, Wa1 = {0.f,0.f,0.f,0.f};
#pragma unroll
      for (int h = 0; h < 2; ++h) {
        bf16x8 vf0 = ldf(Vt2[h] + lo * 64 + ((hi * 8) ^ mLo));
        bf16x8 vf1 = ldf(Vt2[h] + lo * 64 + ((hi * 8 + 32) ^ mLo));
        bf16x8 uf0 = ldf(Ut2[h] + lo * 64 + ((hi * 8) ^ mLo));
        bf16x8 uf1 = ldf(Ut2[h] + lo * 64 + ((hi * 8 + 32) ^ mLo));
        Wa0 = __builtin_amdgcn_mfma_f32_16x16x32_bf16(vf0, bcv(fA0), Wa0, 0, 0, 0);
        Wa1 = __builtin_amdgcn_mfma_f32_16x16x32_bf16(vf1, bcv(fA1), Wa1, 0, 0, 0);
        Wa0 = __builtin_amdgcn_mfma_f32_16x16x32_bf16(uf0, bcv(fB0), Wa0, 0, 0, 0);
        Wa1 = __builtin_amdgcn_mfma_f32_16x16x32_bf16(uf1, bcv(fB1), Wa1, 0, 0, 0);
      }
      f32x4 Wa = Wa0 + Wa1;
      if (kh == 0) {
        if (hi < 2) {
#pragma unroll
          for (int r = 0; r < 4; ++r) {
            int v = 4 * hi + r;
            Ws[v * 64 + (sidx ^ (sx6(v) << 3))] = f2bf(Wa[r]);
          }
        }
      } else {
        if (hi < 2) {
          float4 yo = make_float4(Wa[0], Wa[1], Wa[2], Wa[3]);
          *(float4*)(yb + (size_t)(c * CC + sidx) * DD + v0 + 4 * hi) = yo;
        }
      }
    }
    barrier_lgkm();
    // ---- phase D: S = lam64*S + Ws^T.K ----
    {
      bf16x8 ws0 = ldf(Ws + lo * 64 + ((hi * 8) ^ mLo));
      bf16x8 ws1 = ldf(Ws + lo * 64 + ((hi * 8 + 32) ^ mLo));
#pragma unroll
      for (int t = 0; t < 4; ++t) {
        f32x4 acc = Sa[t] * lam64;
        acc = __builtin_amdgcn_mfma_f32_16x16x32_bf16(ws0, bcv(kt0[t]), acc, 0, 0, 0);
        acc = __builtin_amdgcn_mfma_f32_16x16x32_bf16(ws1, bcv(kt1[t]), acc, 0, 0, 0);
        Sa[t] = acc;
      }
      if (hi < 2) {
#pragma unroll
        for (int t = 0; t < 4; ++t) {
          int kc = 16 * (4 * wid + t) + lo;
#pragma unroll
          for (int r = 0; r < 4; ++r) {
            int v = 4 * hi + r;
            Sb[v * DD + (kc ^ (sx6(v) << 3))] = f2bf(Sa[t][r]);
          }
        }
      }
    }
    if (c + 1 < NC) {
      const u16* ktc = kbt + (size_t)(b * NC + c + 1) * CC * DD;
#pragma unroll
      for (int t = 0; t < 4; ++t) {
        int k = 16 * (4 * wid + t) + lo;
        const u16* rowp = ktc + (size_t)k * 64;
        int m = sx6(k) << 3;
        kt0[t] = *(const u32x4*)(rowp + ((8 * hi) ^ m));
        kt1[t] = *(const u32x4*)(rowp + ((8 * hi + 32) ^ m));
      }
      size_t tbase = ((size_t)(b * NC + c + 1) * 64 + sidx) * 64 + hi * 8;
      const u16* mA = (kh == 0) ? tbs : p1g;
      const u16* mB = (kh == 0) ? tcs : p2g;
      fA0 = *(const u32x4*)(mA + tbase);
      fA1 = *(const u32x4*)(mA + tbase + 32);
      fB0 = *(const u32x4*)(mB + tbase);
      fB1 = *(const u32x4*)(mB + tbase + 32);
    }
    barrier_lgkm();
  }
}

// ---------------------------------------------------------------------------
// K4: LayerNorm in-place on d_out.
// ---------------------------------------------------------------------------
__global__ __launch_bounds__(256) void k_ln(float* __restrict__ y,
                                            const float* __restrict__ gamma,
                                            const float* __restrict__ lbeta) {
  int row = blockIdx.x * 4 + (threadIdx.x >> 6);
  int lane = threadIdx.x & 63;
  float* yr = y + (size_t)row * DD + lane * 8;
  float4 a = *(const float4*)yr;
  float4 b = *(const float4*)(yr + 4);
  float v[8] = {a.x, a.y, a.z, a.w, b.x, b.y, b.z, b.w};
  float s = 0.f, ss = 0.f;
#pragma unroll
  for (int j = 0; j < 8; ++j) {
    s += v[j];
    ss = fmaf(v[j], v[j], ss);
  }
#pragma unroll
  for (int m = 1; m < 64; m <<= 1) {
    s += __shfl_xor(s, m, 64);
    ss += __shfl_xor(ss, m, 64);
  }
  float mu = s * (1.f / DD);
  float var = ss * (1.f / DD) - mu * mu;
  float inv = rsqrtf(var + EPSF);
  const float* gp = gamma + lane * 8;
  const float* bp = lbeta + lane * 8;
  float4 g0 = *(const float4*)gp;
  float4 g1 = *(const float4*)(gp + 4);
  float4 b0 = *(const float4*)bp;
  float4 b1 = *(const float4*)(bp + 4);
  float g[8] = {g0.x, g0.y, g0.z, g0.w, g1.x, g1.y, g1.z, g1.w};
  float bb[8] = {b0.x, b0.y, b0.z, b0.w, b1.x, b1.y, b1.z, b1.w};
#pragma unroll
  for (int j = 0; j < 8; ++j) v[j] = (v[j] - mu) * inv * g[j] + bb[j];
  *(float4*)yr = make_float4(v[0], v[1], v[2], v[3]);
  *(float4*)(yr + 4) = make_float4(v[4], v[5], v[6], v[7]);
}

// ---------------------------------------------------------------------------
extern "C" void kernel_launch(void* const* d_in, const int* in_sizes, int n_in,
                              void* d_out, int out_size, void* d_ws, size_t ws_size,
                              hipStream_t stream) {
  const float* x     = (const float*)d_in[0];
  const float* W     = (const float*)d_in[1];
  const float* eta   = (const float*)d_in[2];
  const float* ll    = (const float*)d_in[3];
  const float* gamma = (const float*)d_in[4];
  const float* lbeta = (const float*)d_in[5];
  float* out = (float*)d_out;

  // ws (u16): kbs 8MB | kbt 8MB | wbb 0.5MB | tbs/tcs/p1/p2 1MB each (~20.5MB)
  u16* kbs = (u16*)d_ws;
  u16* kbt = kbs + (size_t)BB * LL * DD;
  u16* wbb = kbt + (size_t)BB * LL * DD;
  u16* tbs = wbb + (size_t)DD * DD;
  u16* tcs = tbs + (size_t)BB * NC * 64 * 64;
  u16* p1g = tcs + (size_t)BB * NC * 64 * 64;
  u16* p2g = p1g + (size_t)BB * NC * 64 * 64;

  k_pre2<<<640, 256, 0, stream>>>(x, W, kbs, wbb, kbt);
  k_prep5<<<BB * NC, 512, 0, stream>>>(kbs, eta, ll, tbs, tcs, p1g, p2g);
  k_scanC<<<256, 512, 0, stream>>>(kbs, kbt, wbb, tbs, tcs, p1g, p2g, ll, out);
  k_ln<<<2048, 256, 0, stream>>>(out, gamma, lbeta);
}